// Round 7
// baseline (306.475 us; speedup 1.0000x reference)
//
#include <hip/hip_runtime.h>
#include <hip/hip_cooperative_groups.h>
#include <cmath>

namespace cg = cooperative_groups;

namespace {
constexpr int NB = 16384;
constexpr int NS = 50;
constexpr int NK = 5;
constexpr int NH = 32;

typedef __attribute__((ext_vector_type(8))) short bf16x8;
typedef __attribute__((ext_vector_type(4))) float f32x4;

__device__ __forceinline__ float wsum64(float v) {
#pragma unroll
  for (int off = 32; off; off >>= 1) v += __shfl_xor(v, off, 64);
  return v;
}

__device__ __forceinline__ float sigm(float x) { return 1.0f / (1.0f + expf(-x)); }

__device__ __forceinline__ unsigned short f2bf(float f) {
  union { float f; unsigned u; } v; v.f = f;
  unsigned r = v.u + 0x7fffu + ((v.u >> 16) & 1u);
  return (unsigned short)(r >> 16);
}

// ---- Kernel 1: embeddings, sim, top-5, x @ au_W1 via MFMA, au-BN stats ------
// UNCHANGED from R6 (passed twice). Sim/top-k arithmetic is selection-critical.
__global__ __launch_bounds__(512) void k1(
    const int* __restrict__ iid, const int* __restrict__ aid,
    const int* __restrict__ hist_iid, const int* __restrict__ hist_aid,
    const int* __restrict__ hist_rate,
    const float* __restrict__ item_tab, const float* __restrict__ cate_tab,
    const float* __restrict__ au_W1, const float* __restrict__ au_b1,
    float* __restrict__ ws_y, float* __restrict__ ws_w,
    int* __restrict__ ws_hi, int* __restrict__ ws_ha, int* __restrict__ ws_hr,
    double* __restrict__ g_au_sum, double* __restrict__ g_au_sq)
{
  const int tid = threadIdx.x;
  const int lane = tid & 63;
  const int wv = tid >> 6;

  __shared__ alignas(16) unsigned short w1t[48][136];
  __shared__ alignas(16) unsigned short xb[80][136];
  __shared__ float icsh[8][64];
  __shared__ float crossm[80];
  __shared__ float w1c[36], b1s[36];
  __shared__ float psum[36], psq[36];

  for (int e = tid; e < 48 * 136; e += 512) {
    const int n = e / 136, k = e - 136 * n;
    float v = 0.f;
    if (n < 36 && k < 128) {
      const int i = (k < 64) ? k : (k + 1);
      v = au_W1[i * 36 + n];
    }
    w1t[n][k] = f2bf(v);
  }
  if (tid < 36) {
    w1c[tid] = au_W1[64 * 36 + tid];
    b1s[tid] = au_b1[tid];
    psum[tid] = 0.f; psq[tid] = 0.f;
  }

  for (int r = 0; r < 2; r++) {
    const int lm = r * 8 + wv;
    const int row = blockIdx.x * 16 + lm;

    const int iv = iid[row];
    const int cv = aid[row];
    const float ic = (lane < 32) ? item_tab[iv * NH + lane] : cate_tab[cv * NH + lane - 32];
    icsh[wv][lane] = ic;
    const float n1 = sqrtf(wsum64(ic * ic));

    int hi = 0, ha = 0, rv = 0;
    float dotv = 0.f, sim = -INFINITY;
    if (lane < NS) {
      hi = hist_iid[row * NS + lane];
      ha = hist_aid[row * NS + lane];
      rv = hist_rate[row * NS + lane];
      const float4* ip = reinterpret_cast<const float4*>(item_tab + (size_t)hi * NH);
      const float4* cp = reinterpret_cast<const float4*>(cate_tab + (size_t)ha * NH);
      const float* ics = icsh[wv];
      float n2sq = 0.f;
#pragma unroll
      for (int q = 0; q < 8; q++) {
        float4 a = ip[q];
        dotv += ics[4*q+0]*a.x + ics[4*q+1]*a.y + ics[4*q+2]*a.z + ics[4*q+3]*a.w;
        n2sq += a.x*a.x + a.y*a.y + a.z*a.z + a.w*a.w;
      }
#pragma unroll
      for (int q = 0; q < 8; q++) {
        float4 a = cp[q];
        dotv += ics[32+4*q+0]*a.x + ics[32+4*q+1]*a.y + ics[32+4*q+2]*a.z + ics[32+4*q+3]*a.w;
        n2sq += a.x*a.x + a.y*a.y + a.z*a.z + a.w*a.w;
      }
      sim = dotv / fmaxf(n1 * sqrtf(n2sq), 1e-8f);
    }

    float simw = sim;
    const int si = (lane < NS) ? lane : 1000;
    float vals[NK]; int idxs[NK];
#pragma unroll
    for (int rr = 0; rr < NK; rr++) {
      float v = simw; int ii = si;
#pragma unroll
      for (int off = 32; off; off >>= 1) {
        float ov = __shfl_xor(v, off, 64);
        int   oi = __shfl_xor(ii, off, 64);
        if (ov > v || (ov == v && oi < ii)) { v = ov; ii = oi; }
      }
      vals[rr] = v; idxs[rr] = ii;
      if (si == ii) simw = -INFINITY;
    }

    const float ssumw = vals[0] + vals[1] + vals[2] + vals[3] + vals[4] + 1e-8f;
#pragma unroll
    for (int k = 0; k < NK; k++) {
      const float wk = vals[k] / ssumw;
      const float crossk = wk * __shfl(dotv, idxs[k], 64);
      const int hik = __shfl(hi, idxs[k], 64);
      const int hak = __shfl(ha, idxs[k], 64);
      const int rvk = __shfl(rv, idxs[k], 64);
      const float e = (lane < 32) ? item_tab[hik * NH + lane] : cate_tab[hak * NH + lane - 32];
      const int m = lm * 5 + k;
      xb[m][lane] = f2bf(wk * e);
      xb[m][64 + lane] = f2bf(ic);
      if (lane == 0) crossm[m] = crossk;
      if (lane == k) {
        ws_w[row * NK + k] = wk;
        ws_hi[row * NK + k] = hik;
        ws_ha[row * NK + k] = hak;
        ws_hr[row * NK + k] = rvk;
      }
    }
  }
  __syncthreads();

  const int l15 = lane & 15, lhi = lane >> 4;
  for (int t = wv; t < 15; t += 8) {
    const int mt = t / 3, nt = t - 3 * mt;
    f32x4 acc = {0.f, 0.f, 0.f, 0.f};
#pragma unroll
    for (int ks = 0; ks < 4; ks++) {
      const int k0 = ks * 32 + lhi * 8;
      const bf16x8 a = *reinterpret_cast<const bf16x8*>(&xb[mt * 16 + l15][k0]);
      const bf16x8 b = *reinterpret_cast<const bf16x8*>(&w1t[nt * 16 + l15][k0]);
      acc = __builtin_amdgcn_mfma_f32_16x16x32_bf16(a, b, acc, 0, 0, 0);
    }
    const int n = nt * 16 + l15;
    if (n < 36) {
      const float w1cn = w1c[n], b1n = b1s[n];
      float ls = 0.f, lq = 0.f;
#pragma unroll
      for (int reg = 0; reg < 4; reg++) {
        const int m = mt * 16 + 4 * lhi + reg;
        const float y = acc[reg] + b1n + crossm[m] * w1cn;
        ws_y[(size_t)(blockIdx.x * 80 + m) * 36 + n] = y;
        ls += y; lq += y * y;
      }
      atomicAdd(&psum[n], ls);
      atomicAdd(&psq[n], lq);
    }
  }
  __syncthreads();
  if (tid < 36) {
    atomicAdd(&g_au_sum[tid], (double)psum[tid]);
    atomicAdd(&g_au_sq[tid], (double)psq[tid]);
  }
}

// ---- Fused cooperative kernel: k3 + k5 + k7 + k8 ---------------------------
// grid 512 x 512thr, 32 rows/block, 2 blocks/CU (LDS 61.8 KB, VGPR<=128).
struct KfParams {
  const int* iid; const int* aid; const int* lb;
  const float* item_tab; const float* cate_tab; const float* rate_tab;
  const float* au_alpha; const float* au_beta; const float* au_gamma;
  const float* au_bbeta; const float* au_W2; const float* au_b2;
  const float* l1_W; const float* l1_b;
  const float* d1_alpha; const float* d1_beta; const float* d1_gamma; const float* d1_bbeta;
  const float* l2_W; const float* l2_b;
  const float* d2_alpha; const float* d2_beta; const float* d2_gamma; const float* d2_bbeta;
  const float* l3_W; const float* l3_b;
  const float* ws_y; const float* ws_w;
  const int* ws_hi; const int* ws_ha; const int* ws_hr;
  const double* g_au_sum; const double* g_au_sq;
  float* ws_h1; double* g_d1_sum; double* g_d1_sq;
  float* ws_h2; double* g_d2_sum; double* g_d2_sq;
  float* out; double* g_loss;
};

__global__ __launch_bounds__(512, 4) void kf(KfParams P)
{
  const int tid = threadIdx.x, lane = tid & 63, wv = tid >> 6;
  const int bx = blockIdx.x;
  const int base = bx * 32;
  cg::grid_group gg = cg::this_grid();

  __shared__ union SU {
    struct {
      alignas(16) unsigned short l1t[80][168];   // 26880 B
      alignas(16) unsigned short resb[32][168];  // 10752 B
      float ysh[160][37];                        // 23680 B (pad 37: no bank clash)
      float aoutsh[160];
      float asc[36], bsc[36], bets[36], alps[36], w2s[36];
      float psum[80], psq[80];
    } p2;
    struct {
      alignas(16) unsigned short l2t[48][104];
      alignas(16) unsigned short h1b[32][104];
      float a1[80], c1[80];
      float psum[40], psq[40];
    } p3;
    struct {
      float a2[40], c2[40];
      float wls[8];
    } p4;
  } su;

  const int l15 = lane & 15, lhi = lane >> 4;

  // ================= Phase 2 (k3): dice3 + au_out + final_hist + l1 GEMM ====
  for (int e = tid; e < 80 * 168; e += 512) {
    const int n = e / 168, k = e - 168 * n;
    su.p2.l1t[n][k] = (k < 160) ? f2bf(P.l1_W[k * 80 + n]) : (unsigned short)0;
  }
  for (int e = tid; e < 160 * 36; e += 512) {
    su.p2.ysh[e / 36][e % 36] = P.ws_y[(size_t)bx * 5760 + e];
  }
  if (tid < 36) {
    const double m = P.g_au_sum[tid] * (1.0 / ((double)NB * NK));
    const double var = P.g_au_sq[tid] * (1.0 / ((double)NB * NK)) - m * m;
    const float rstd = (float)(1.0 / sqrt(var + 1e-8));
    const float g = P.au_gamma[tid] * rstd;
    su.p2.asc[tid] = g; su.p2.bsc[tid] = P.au_bbeta[tid] - (float)m * g;
    su.p2.bets[tid] = P.au_beta[tid];
    su.p2.alps[tid] = P.au_alpha[tid];
    su.p2.w2s[tid] = P.au_W2[tid];
  }
  if (tid < 80) { su.p2.psum[tid] = 0.f; su.p2.psq[tid] = 0.f; }
  __syncthreads();

  // aout: one thread per (row,k); sequential dot, no cross-lane ops
  const float bias2 = P.au_b2[0];
  if (tid < 160) {
    float acc = 0.f;
#pragma unroll
    for (int j = 0; j < 36; j++) {
      const float yv = su.p2.ysh[tid][j];
      const float bn = yv * su.p2.asc[j] + su.p2.bsc[j];
      const float xn = sigm(su.p2.bets[j] * bn);
      acc = fmaf(su.p2.alps[j] * (1.f - xn) * yv + xn * yv, su.p2.w2s[j], acc);
    }
    su.p2.aoutsh[tid] = acc + bias2;
  }
  __syncthreads();

  for (int r = 0; r < 4; r++) {
    const int lm = r * 8 + wv;
    const int row = base + lm;
    const int iv = P.iid[row], cv = P.aid[row];
    const float ic = (lane < 32) ? P.item_tab[iv * NH + lane] : P.cate_tab[cv * NH + lane - 32];
    float fh0 = 0.f, fh1 = 0.f;
#pragma unroll
    for (int k = 0; k < NK; k++) {
      const int hik = P.ws_hi[row * NK + k];
      const int hak = P.ws_ha[row * NK + k];
      const int rvk = P.ws_hr[row * NK + k];
      const float wk = P.ws_w[row * NK + k];
      const float aok = su.p2.aoutsh[lm * 5 + k];
      const float e = (lane < 32) ? P.item_tab[hik * NH + lane] : P.cate_tab[hak * NH + lane - 32];
      fh0 = fmaf(wk * e, aok, fh0);
      if (lane < 32) fh1 = fmaf(P.rate_tab[rvk * NH + lane], aok, fh1);
    }
    su.p2.resb[lm][lane] = f2bf(ic);
    su.p2.resb[lm][64 + lane] = f2bf(fh0);
    if (lane < 32) su.p2.resb[lm][128 + lane] = f2bf(fh1);
  }
  __syncthreads();

  // GEMM M=32 (2 mt) x N=80 (5 nt), K=160 (5 steps)
  for (int t = wv; t < 10; t += 8) {
    const int mt = t / 5, nt = t - 5 * mt;
    f32x4 acc = {0.f, 0.f, 0.f, 0.f};
#pragma unroll
    for (int ks = 0; ks < 5; ks++) {
      const int k0 = ks * 32 + lhi * 8;
      const bf16x8 a = *reinterpret_cast<const bf16x8*>(&su.p2.resb[mt * 16 + l15][k0]);
      const bf16x8 b = *reinterpret_cast<const bf16x8*>(&su.p2.l1t[nt * 16 + l15][k0]);
      acc = __builtin_amdgcn_mfma_f32_16x16x32_bf16(a, b, acc, 0, 0, 0);
    }
    const int n = nt * 16 + l15;
    const float bn = P.l1_b[n];
    float ls = 0.f, lq = 0.f;
#pragma unroll
    for (int reg = 0; reg < 4; reg++) {
      const int m = mt * 16 + 4 * lhi + reg;
      const float h = acc[reg] + bn;
      P.ws_h1[(size_t)(base + m) * 80 + n] = h;
      ls += h; lq += h * h;
    }
    atomicAdd(&su.p2.psum[n], ls);
    atomicAdd(&su.p2.psq[n], lq);
  }
  __syncthreads();
  if (tid < 80) {
    atomicAdd(&P.g_d1_sum[tid], (double)su.p2.psum[tid]);
    atomicAdd(&P.g_d1_sq[tid], (double)su.p2.psq[tid]);
  }

  gg.sync();

  // ================= Phase 3 (k5): dice2(h1) + l2 GEMM =======================
  for (int e = tid; e < 48 * 104; e += 512) {
    const int n = e / 104, k = e - 104 * n;
    su.p3.l2t[n][k] = (n < 40 && k < 80) ? f2bf(P.l2_W[k * 40 + n]) : (unsigned short)0;
  }
  if (tid < 80) {
    const double m = P.g_d1_sum[tid] * (1.0 / (double)NB);
    const double var = P.g_d1_sq[tid] * (1.0 / (double)NB) - m * m;
    const float rstd = (float)(1.0 / sqrt(var + 1e-8));
    const float g = P.d1_gamma[tid] * rstd;
    su.p3.a1[tid] = g; su.p3.c1[tid] = P.d1_bbeta[tid] - (float)m * g;
  }
  if (tid < 40) { su.p3.psum[tid] = 0.f; su.p3.psq[tid] = 0.f; }
  __syncthreads();

  for (int r = 0; r < 4; r++) {
    const int lm = r * 8 + wv;
    const int row = base + lm;
    {
      const float v = P.ws_h1[(size_t)row * 80 + lane];
      const float bn = v * su.p3.a1[lane] + su.p3.c1[lane];
      const float xn = sigm(P.d1_beta[lane] * bn);
      su.p3.h1b[lm][lane] = f2bf(P.d1_alpha[lane] * (1.f - xn) * v + xn * v);
    }
    const int o = 64 + lane;
    if (lane < 16) {
      const float v = P.ws_h1[(size_t)row * 80 + o];
      const float bn = v * su.p3.a1[o] + su.p3.c1[o];
      const float xn = sigm(P.d1_beta[o] * bn);
      su.p3.h1b[lm][o] = f2bf(P.d1_alpha[o] * (1.f - xn) * v + xn * v);
    } else if (lane < 32) {
      su.p3.h1b[lm][o] = 0;
    }
  }
  __syncthreads();

  // GEMM M=32 (2 mt) x N=48 (3 nt), K=96 (3 steps)
  for (int t = wv; t < 6; t += 8) {
    const int mt = t / 3, nt = t - 3 * mt;
    f32x4 acc = {0.f, 0.f, 0.f, 0.f};
#pragma unroll
    for (int ks = 0; ks < 3; ks++) {
      const int k0 = ks * 32 + lhi * 8;
      const bf16x8 a = *reinterpret_cast<const bf16x8*>(&su.p3.h1b[mt * 16 + l15][k0]);
      const bf16x8 b = *reinterpret_cast<const bf16x8*>(&su.p3.l2t[nt * 16 + l15][k0]);
      acc = __builtin_amdgcn_mfma_f32_16x16x32_bf16(a, b, acc, 0, 0, 0);
    }
    const int n = nt * 16 + l15;
    if (n < 40) {
      const float bn = P.l2_b[n];
      float ls = 0.f, lq = 0.f;
#pragma unroll
      for (int reg = 0; reg < 4; reg++) {
        const int m = mt * 16 + 4 * lhi + reg;
        const float h = acc[reg] + bn;
        P.ws_h2[(size_t)(base + m) * 40 + n] = h;
        ls += h; lq += h * h;
      }
      atomicAdd(&su.p3.psum[n], ls);
      atomicAdd(&su.p3.psq[n], lq);
    }
  }
  __syncthreads();
  if (tid < 40) {
    atomicAdd(&P.g_d2_sum[tid], (double)su.p3.psum[tid]);
    atomicAdd(&P.g_d2_sq[tid], (double)su.p3.psq[tid]);
  }

  gg.sync();

  // ================= Phase 4 (k7): dice2(h2) + logits + loss =================
  if (tid < 40) {
    const double m = P.g_d2_sum[tid] * (1.0 / (double)NB);
    const double var = P.g_d2_sq[tid] * (1.0 / (double)NB) - m * m;
    const float rstd = (float)(1.0 / sqrt(var + 1e-8));
    const float g = P.d2_gamma[tid] * rstd;
    su.p4.a2[tid] = g; su.p4.c2[tid] = P.d2_bbeta[tid] - (float)m * g;
  }
  __syncthreads();

  float wj = 0, b2j = 0, c2j = 0, betaj = 0, alphaj = 0;
  if (lane < 40) {
    wj = P.l3_W[lane]; b2j = su.p4.a2[lane]; c2j = su.p4.c2[lane];
    betaj = P.d2_beta[lane]; alphaj = P.d2_alpha[lane];
  }
  const float b3 = P.l3_b[0];

  float lacc = 0.f;
  for (int r = 0; r < 4; r++) {
    const int row = base + r * 8 + wv;
    float p = 0.f;
    if (lane < 40) {
      const float v = P.ws_h2[(size_t)row * 40 + lane];
      const float bn = v * b2j + c2j;
      const float xn = sigm(betaj * bn);
      p = (alphaj * (1.f - xn) * v + xn * v) * wj;
    }
    const float logit = wsum64(p) + b3;
    if (lane == 0) {
      P.out[row] = 1.f / (1.f + expf(-logit));
      const float lab = (float)P.lb[row];
      lacc += fmaxf(logit, 0.f) - logit * lab + log1pf(expf(-fabsf(logit)));
    }
  }
  if (lane == 0) su.p4.wls[wv] = lacc;
  __syncthreads();
  if (tid == 0) {
    float s = 0.f;
#pragma unroll
    for (int w = 0; w < 8; w++) s += su.p4.wls[w];
    atomicAdd(P.g_loss, (double)s);
  }

  gg.sync();

  // ================= Phase 5 (k8): finalize loss =============================
  if (bx == 0 && tid == 0) P.out[NB] = (float)(P.g_loss[0] * (1.0 / (double)NB));
}

} // namespace

extern "C" void kernel_launch(void* const* d_in, const int* in_sizes, int n_in,
                              void* d_out, int out_size, void* d_ws, size_t ws_size,
                              hipStream_t stream) {
  const int* iid       = (const int*)d_in[0];
  const int* aid       = (const int*)d_in[1];
  const int* lb        = (const int*)d_in[2];
  const int* hist_iid  = (const int*)d_in[3];
  const int* hist_aid  = (const int*)d_in[4];
  const int* hist_rate = (const int*)d_in[5];
  const float* item_tab = (const float*)d_in[6];
  const float* cate_tab = (const float*)d_in[7];
  const float* rate_tab = (const float*)d_in[8];
  const float* au_W1    = (const float*)d_in[9];
  const float* au_b1    = (const float*)d_in[10];
  const float* au_alpha = (const float*)d_in[11];
  const float* au_beta  = (const float*)d_in[12];
  const float* au_gamma = (const float*)d_in[13];
  const float* au_bbeta = (const float*)d_in[14];
  const float* au_W2    = (const float*)d_in[15];
  const float* au_b2    = (const float*)d_in[16];
  const float* l1_W     = (const float*)d_in[17];
  const float* l1_b     = (const float*)d_in[18];
  const float* d1_alpha = (const float*)d_in[19];
  const float* d1_beta  = (const float*)d_in[20];
  const float* d1_gamma = (const float*)d_in[21];
  const float* d1_bbeta = (const float*)d_in[22];
  const float* l2_W     = (const float*)d_in[23];
  const float* l2_b     = (const float*)d_in[24];
  const float* d2_alpha = (const float*)d_in[25];
  const float* d2_beta  = (const float*)d_in[26];
  const float* d2_gamma = (const float*)d_in[27];
  const float* d2_bbeta = (const float*)d_in[28];
  const float* l3_W     = (const float*)d_in[29];
  const float* l3_b     = (const float*)d_in[30];
  float* out = (float*)d_out;

  double* g = (double*)d_ws;
  double* g_au_sum = g;
  double* g_au_sq  = g + 36;
  double* g_d1_sum = g + 72;
  double* g_d1_sq  = g + 152;
  double* g_d2_sum = g + 232;
  double* g_d2_sq  = g + 272;
  double* g_loss   = g + 312;
  float* fbase  = (float*)((char*)d_ws + 4096);
  float* ws_y   = fbase;                       // NB*180
  float* ws_w   = fbase + (size_t)NB * 180;    // NB*5
  float* ws_h1  = fbase + (size_t)NB * 185;    // NB*80
  float* ws_h2  = fbase + (size_t)NB * 265;    // NB*40
  int*   ws_hi  = (int*)(fbase + (size_t)NB * 305);  // NB*5
  int*   ws_ha  = ws_hi + (size_t)NB * NK;
  int*   ws_hr  = ws_ha + (size_t)NB * NK;

  hipMemsetAsync(d_ws, 0, 313 * sizeof(double), stream);
  k1<<<dim3(NB / 16), 512, 0, stream>>>(iid, aid, hist_iid, hist_aid, hist_rate,
                              item_tab, cate_tab, au_W1, au_b1,
                              ws_y, ws_w, ws_hi, ws_ha, ws_hr, g_au_sum, g_au_sq);

  KfParams kp;
  kp.iid = iid; kp.aid = aid; kp.lb = lb;
  kp.item_tab = item_tab; kp.cate_tab = cate_tab; kp.rate_tab = rate_tab;
  kp.au_alpha = au_alpha; kp.au_beta = au_beta; kp.au_gamma = au_gamma;
  kp.au_bbeta = au_bbeta; kp.au_W2 = au_W2; kp.au_b2 = au_b2;
  kp.l1_W = l1_W; kp.l1_b = l1_b;
  kp.d1_alpha = d1_alpha; kp.d1_beta = d1_beta; kp.d1_gamma = d1_gamma; kp.d1_bbeta = d1_bbeta;
  kp.l2_W = l2_W; kp.l2_b = l2_b;
  kp.d2_alpha = d2_alpha; kp.d2_beta = d2_beta; kp.d2_gamma = d2_gamma; kp.d2_bbeta = d2_bbeta;
  kp.l3_W = l3_W; kp.l3_b = l3_b;
  kp.ws_y = ws_y; kp.ws_w = ws_w; kp.ws_hi = ws_hi; kp.ws_ha = ws_ha; kp.ws_hr = ws_hr;
  kp.g_au_sum = g_au_sum; kp.g_au_sq = g_au_sq;
  kp.ws_h1 = ws_h1; kp.g_d1_sum = g_d1_sum; kp.g_d1_sq = g_d1_sq;
  kp.ws_h2 = ws_h2; kp.g_d2_sum = g_d2_sum; kp.g_d2_sq = g_d2_sq;
  kp.out = out; kp.g_loss = g_loss;

  void* kargs[] = { (void*)&kp };
  hipLaunchCooperativeKernel((const void*)kf, dim3(512), dim3(512), kargs, 0, stream);
}

// Round 8
// 189.964 us; speedup vs baseline: 1.6133x; 1.6133x over previous
//
#include <hip/hip_runtime.h>
#include <cmath>

namespace {
constexpr int NB = 16384;
constexpr int NS = 50;
constexpr int NK = 5;
constexpr int NH = 32;

typedef __attribute__((ext_vector_type(8))) short bf16x8;
typedef __attribute__((ext_vector_type(4))) float f32x4;

__device__ __forceinline__ float wsum64(float v) {
#pragma unroll
  for (int off = 32; off; off >>= 1) v += __shfl_xor(v, off, 64);
  return v;
}

__device__ __forceinline__ float sigm(float x) { return 1.0f / (1.0f + expf(-x)); }

__device__ __forceinline__ unsigned short f2bf(float f) {
  union { float f; unsigned u; } v; v.f = f;
  unsigned r = v.u + 0x7fffu + ((v.u >> 16) & 1u);
  return (unsigned short)(r >> 16);
}

// ---- Kernel 1: embeddings, sim, top-5, x @ au_W1 via MFMA, au-BN stats ------
// 512 thr = 8 waves; 8 rows/block, 1 row per wave (max independent chains).
// Sim/top-k arithmetic is R4/R6-verbatim per lane: selection-critical.
__global__ __launch_bounds__(512) void k1(
    const int* __restrict__ iid, const int* __restrict__ aid,
    const int* __restrict__ hist_iid, const int* __restrict__ hist_aid,
    const int* __restrict__ hist_rate,
    const float* __restrict__ item_tab, const float* __restrict__ cate_tab,
    const float* __restrict__ au_W1, const float* __restrict__ au_b1,
    float* __restrict__ ws_y, float* __restrict__ ws_w,
    int* __restrict__ ws_hi, int* __restrict__ ws_ha, int* __restrict__ ws_hr,
    double* __restrict__ g_au_sum, double* __restrict__ g_au_sq)
{
  const int tid = threadIdx.x;
  const int lane = tid & 63;
  const int wv = tid >> 6;

  __shared__ alignas(16) unsigned short w1t[48][136]; // B: [n][k], bf16, k<128
  __shared__ alignas(16) unsigned short xb[48][136];  // A: [m][k], m=wv*5+k (<40), pad 40..47 zero
  __shared__ float icsh[8][64];
  __shared__ float crossm[40];
  __shared__ float w1c[36], b1s[36];
  __shared__ float psum[36], psq[36];

  for (int e = tid; e < 48 * 136; e += 512) {
    const int n = e / 136, k = e - 136 * n;
    float v = 0.f;
    if (n < 36 && k < 128) {
      const int i = (k < 64) ? k : (k + 1);
      v = au_W1[i * 36 + n];
    }
    w1t[n][k] = f2bf(v);
  }
  // zero the pad rows of xb (m = 40..47) so GEMM reads are finite
  for (int e = tid; e < 8 * 136; e += 512) {
    xb[40 + e / 136][e - 136 * (e / 136)] = 0;
  }
  if (tid < 36) {
    w1c[tid] = au_W1[64 * 36 + tid];
    b1s[tid] = au_b1[tid];
    psum[tid] = 0.f; psq[tid] = 0.f;
  }

  {
    const int row = blockIdx.x * 8 + wv;

    const int iv = iid[row];
    const int cv = aid[row];
    const float ic = (lane < 32) ? item_tab[iv * NH + lane] : cate_tab[cv * NH + lane - 32];
    icsh[wv][lane] = ic;
    const float n1 = sqrtf(wsum64(ic * ic));

    int hi = 0, ha = 0, rv = 0;
    float dotv = 0.f, sim = -INFINITY;
    if (lane < NS) {
      hi = hist_iid[row * NS + lane];
      ha = hist_aid[row * NS + lane];
      rv = hist_rate[row * NS + lane];
      const float4* ip = reinterpret_cast<const float4*>(item_tab + (size_t)hi * NH);
      const float4* cp = reinterpret_cast<const float4*>(cate_tab + (size_t)ha * NH);
      const float* ics = icsh[wv];
      float n2sq = 0.f;
#pragma unroll
      for (int q = 0; q < 8; q++) {
        float4 a = ip[q];
        dotv += ics[4*q+0]*a.x + ics[4*q+1]*a.y + ics[4*q+2]*a.z + ics[4*q+3]*a.w;
        n2sq += a.x*a.x + a.y*a.y + a.z*a.z + a.w*a.w;
      }
#pragma unroll
      for (int q = 0; q < 8; q++) {
        float4 a = cp[q];
        dotv += ics[32+4*q+0]*a.x + ics[32+4*q+1]*a.y + ics[32+4*q+2]*a.z + ics[32+4*q+3]*a.w;
        n2sq += a.x*a.x + a.y*a.y + a.z*a.z + a.w*a.w;
      }
      sim = dotv / fmaxf(n1 * sqrtf(n2sq), 1e-8f);
    }

    // top-5: descending value, ascending-index tie-break
    float simw = sim;
    const int si = (lane < NS) ? lane : 1000;
    float vals[NK]; int idxs[NK];
#pragma unroll
    for (int rr = 0; rr < NK; rr++) {
      float v = simw; int ii = si;
#pragma unroll
      for (int off = 32; off; off >>= 1) {
        float ov = __shfl_xor(v, off, 64);
        int   oi = __shfl_xor(ii, off, 64);
        if (ov > v || (ov == v && oi < ii)) { v = ov; ii = oi; }
      }
      vals[rr] = v; idxs[rr] = ii;
      if (si == ii) simw = -INFINITY;
    }

    const float ssumw = vals[0] + vals[1] + vals[2] + vals[3] + vals[4] + 1e-8f;
#pragma unroll
    for (int k = 0; k < NK; k++) {
      const float wk = vals[k] / ssumw;
      const float crossk = wk * __shfl(dotv, idxs[k], 64);
      const int hik = __shfl(hi, idxs[k], 64);
      const int hak = __shfl(ha, idxs[k], 64);
      const int rvk = __shfl(rv, idxs[k], 64);
      const float e = (lane < 32) ? item_tab[hik * NH + lane] : cate_tab[hak * NH + lane - 32];
      const int m = wv * 5 + k;
      xb[m][lane] = f2bf(wk * e);
      xb[m][64 + lane] = f2bf(ic);
      if (lane == 0) crossm[m] = crossk;
      if (lane == k) {
        ws_w[row * NK + k] = wk;
        ws_hi[row * NK + k] = hik;
        ws_ha[row * NK + k] = hak;
        ws_hr[row * NK + k] = rvk;
      }
    }
  }
  __syncthreads();

  // MFMA GEMM: M=40->48 (3 tiles), N=36->48 (3 tiles), K=128 (4 steps)
  const int l15 = lane & 15, lhi = lane >> 4;
  for (int t = wv; t < 9; t += 8) {
    const int mt = t / 3, nt = t - 3 * mt;
    f32x4 acc = {0.f, 0.f, 0.f, 0.f};
#pragma unroll
    for (int ks = 0; ks < 4; ks++) {
      const int k0 = ks * 32 + lhi * 8;
      const bf16x8 a = *reinterpret_cast<const bf16x8*>(&xb[mt * 16 + l15][k0]);
      const bf16x8 b = *reinterpret_cast<const bf16x8*>(&w1t[nt * 16 + l15][k0]);
      acc = __builtin_amdgcn_mfma_f32_16x16x32_bf16(a, b, acc, 0, 0, 0);
    }
    const int n = nt * 16 + l15;
    if (n < 36) {
      const float w1cn = w1c[n], b1n = b1s[n];
      float ls = 0.f, lq = 0.f;
      bool any = false;
#pragma unroll
      for (int reg = 0; reg < 4; reg++) {
        const int m = mt * 16 + 4 * lhi + reg;
        if (m < 40) {
          const float y = acc[reg] + b1n + crossm[m] * w1cn;
          ws_y[(size_t)(blockIdx.x * 40 + m) * 36 + n] = y;
          ls += y; lq += y * y;
          any = true;
        }
      }
      if (any) {
        atomicAdd(&psum[n], ls);
        atomicAdd(&psq[n], lq);
      }
    }
  }
  __syncthreads();
  if (tid < 36) {
    atomicAdd(&g_au_sum[tid], (double)psum[tid]);
    atomicAdd(&g_au_sq[tid], (double)psq[tid]);
  }
}

// ---- Kernel 3: dice3 (LDS-staged aout), final_hist, res @ l1_W, d1 stats ----
// 512 thr = 8 waves; 32 rows/block (grid 512). aout phase has no shfl chains.
__global__ __launch_bounds__(512) void k3(
    const int* __restrict__ iid, const int* __restrict__ aid,
    const float* __restrict__ item_tab, const float* __restrict__ cate_tab,
    const float* __restrict__ rate_tab,
    const float* __restrict__ au_alpha, const float* __restrict__ au_beta,
    const float* __restrict__ au_gamma, const float* __restrict__ au_bbeta,
    const float* __restrict__ au_W2, const float* __restrict__ au_b2,
    const float* __restrict__ l1_W, const float* __restrict__ l1_b,
    const float* __restrict__ ws_y, const float* __restrict__ ws_w,
    const int* __restrict__ ws_hi, const int* __restrict__ ws_ha,
    const int* __restrict__ ws_hr,
    const double* __restrict__ g_au_sum, const double* __restrict__ g_au_sq,
    float* __restrict__ ws_h1, double* __restrict__ g_d1_sum, double* __restrict__ g_d1_sq)
{
  const int tid = threadIdx.x, lane = tid & 63, wv = tid >> 6;
  const int base = blockIdx.x * 32;
  __shared__ alignas(16) unsigned short l1t[80][168];
  __shared__ alignas(16) unsigned short resb[32][168];
  __shared__ float ysh[160][37];
  __shared__ float aoutsh[160];
  __shared__ float asc[36], bsc[36], bets[36], alps[36], w2s[36];
  __shared__ float psum[80], psq[80];

  for (int e = tid; e < 80 * 168; e += 512) {
    const int n = e / 168, k = e - 168 * n;
    l1t[n][k] = (k < 160) ? f2bf(l1_W[k * 80 + n]) : (unsigned short)0;
  }
  for (int e = tid; e < 160 * 36; e += 512) {
    ysh[e / 36][e % 36] = ws_y[(size_t)base * 180 + e];
  }
  if (tid < 36) {
    const double m = g_au_sum[tid] * (1.0 / ((double)NB * NK));
    const double var = g_au_sq[tid] * (1.0 / ((double)NB * NK)) - m * m;
    const float rstd = (float)(1.0 / sqrt(var + 1e-8));
    const float g = au_gamma[tid] * rstd;
    asc[tid] = g; bsc[tid] = au_bbeta[tid] - (float)m * g;
    bets[tid] = au_beta[tid];
    alps[tid] = au_alpha[tid];
    w2s[tid] = au_W2[tid];
  }
  if (tid < 80) { psum[tid] = 0.f; psq[tid] = 0.f; }
  __syncthreads();

  const float bias2 = au_b2[0];
  if (tid < 160) {
    float acc = 0.f;
#pragma unroll
    for (int j = 0; j < 36; j++) {
      const float yv = ysh[tid][j];
      const float bn = yv * asc[j] + bsc[j];
      const float xn = sigm(bets[j] * bn);
      acc = fmaf(alps[j] * (1.f - xn) * yv + xn * yv, w2s[j], acc);
    }
    aoutsh[tid] = acc + bias2;
  }
  __syncthreads();

  for (int r = 0; r < 4; r++) {
    const int lm = r * 8 + wv;
    const int row = base + lm;
    const int iv = iid[row], cv = aid[row];
    const float ic = (lane < 32) ? item_tab[iv * NH + lane] : cate_tab[cv * NH + lane - 32];
    float fh0 = 0.f, fh1 = 0.f;
#pragma unroll
    for (int k = 0; k < NK; k++) {
      const int hik = ws_hi[row * NK + k];
      const int hak = ws_ha[row * NK + k];
      const int rvk = ws_hr[row * NK + k];
      const float wk = ws_w[row * NK + k];
      const float aok = aoutsh[lm * 5 + k];
      const float e = (lane < 32) ? item_tab[hik * NH + lane] : cate_tab[hak * NH + lane - 32];
      fh0 = fmaf(wk * e, aok, fh0);
      if (lane < 32) fh1 = fmaf(rate_tab[rvk * NH + lane], aok, fh1);
    }
    resb[lm][lane] = f2bf(ic);
    resb[lm][64 + lane] = f2bf(fh0);
    if (lane < 32) resb[lm][128 + lane] = f2bf(fh1);
  }
  __syncthreads();

  // GEMM M=32 (2 mt) x N=80 (5 nt), K=160 (5 steps)
  const int l15 = lane & 15, lhi = lane >> 4;
  for (int t = wv; t < 10; t += 8) {
    const int mt = t / 5, nt = t - 5 * mt;
    f32x4 acc = {0.f, 0.f, 0.f, 0.f};
#pragma unroll
    for (int ks = 0; ks < 5; ks++) {
      const int k0 = ks * 32 + lhi * 8;
      const bf16x8 a = *reinterpret_cast<const bf16x8*>(&resb[mt * 16 + l15][k0]);
      const bf16x8 b = *reinterpret_cast<const bf16x8*>(&l1t[nt * 16 + l15][k0]);
      acc = __builtin_amdgcn_mfma_f32_16x16x32_bf16(a, b, acc, 0, 0, 0);
    }
    const int n = nt * 16 + l15;
    const float bn = l1_b[n];
    float ls = 0.f, lq = 0.f;
#pragma unroll
    for (int reg = 0; reg < 4; reg++) {
      const int m = mt * 16 + 4 * lhi + reg;
      const float h = acc[reg] + bn;
      ws_h1[(size_t)(base + m) * 80 + n] = h;
      ls += h; lq += h * h;
    }
    atomicAdd(&psum[n], ls);
    atomicAdd(&psq[n], lq);
  }
  __syncthreads();
  if (tid < 80) {
    atomicAdd(&g_d1_sum[tid], (double)psum[tid]);
    atomicAdd(&g_d1_sq[tid], (double)psq[tid]);
  }
}

// ---- Kernel 5: dice2(h1), h @ l2_W via MFMA, d2 stats -----------------------
__global__ __launch_bounds__(512) void k5(
    const float* __restrict__ d1_alpha, const float* __restrict__ d1_beta,
    const float* __restrict__ d1_gamma, const float* __restrict__ d1_bbeta,
    const float* __restrict__ l2_W, const float* __restrict__ l2_b,
    const float* __restrict__ ws_h1,
    const double* __restrict__ g_d1_sum, const double* __restrict__ g_d1_sq,
    float* __restrict__ ws_h2, double* __restrict__ g_d2_sum, double* __restrict__ g_d2_sq)
{
  const int tid = threadIdx.x, lane = tid & 63, wv = tid >> 6;
  __shared__ alignas(16) unsigned short l2t[48][104];
  __shared__ alignas(16) unsigned short h1b[32][104];
  __shared__ float a1[80], c1[80];
  __shared__ float psum[40], psq[40];

  for (int e = tid; e < 48 * 104; e += 512) {
    const int n = e / 104, k = e - 104 * n;
    l2t[n][k] = (n < 40 && k < 80) ? f2bf(l2_W[k * 40 + n]) : (unsigned short)0;
  }
  if (tid < 80) {
    const double m = g_d1_sum[tid] * (1.0 / (double)NB);
    const double var = g_d1_sq[tid] * (1.0 / (double)NB) - m * m;
    const float rstd = (float)(1.0 / sqrt(var + 1e-8));
    const float g = d1_gamma[tid] * rstd;
    a1[tid] = g; c1[tid] = d1_bbeta[tid] - (float)m * g;
  }
  if (tid < 40) { psum[tid] = 0.f; psq[tid] = 0.f; }
  __syncthreads();

  for (int r = 0; r < 4; r++) {
    const int lm = r * 8 + wv;
    const int row = blockIdx.x * 32 + lm;
    {
      const float v = ws_h1[(size_t)row * 80 + lane];
      const float bn = v * a1[lane] + c1[lane];
      const float xn = sigm(d1_beta[lane] * bn);
      h1b[lm][lane] = f2bf(d1_alpha[lane] * (1.f - xn) * v + xn * v);
    }
    const int o = 64 + lane;
    if (lane < 16) {
      const float v = ws_h1[(size_t)row * 80 + o];
      const float bn = v * a1[o] + c1[o];
      const float xn = sigm(d1_beta[o] * bn);
      h1b[lm][o] = f2bf(d1_alpha[o] * (1.f - xn) * v + xn * v);
    } else if (lane < 32) {
      h1b[lm][o] = 0;
    }
  }
  __syncthreads();

  const int l15 = lane & 15, lhi = lane >> 4;
  for (int t = wv; t < 6; t += 8) {
    const int mt = t / 3, nt = t - 3 * mt;
    f32x4 acc = {0.f, 0.f, 0.f, 0.f};
#pragma unroll
    for (int ks = 0; ks < 3; ks++) {
      const int k0 = ks * 32 + lhi * 8;
      const bf16x8 a = *reinterpret_cast<const bf16x8*>(&h1b[mt * 16 + l15][k0]);
      const bf16x8 b = *reinterpret_cast<const bf16x8*>(&l2t[nt * 16 + l15][k0]);
      acc = __builtin_amdgcn_mfma_f32_16x16x32_bf16(a, b, acc, 0, 0, 0);
    }
    const int n = nt * 16 + l15;
    if (n < 40) {
      const float bn = l2_b[n];
      float ls = 0.f, lq = 0.f;
#pragma unroll
      for (int reg = 0; reg < 4; reg++) {
        const int m = mt * 16 + 4 * lhi + reg;
        const float h = acc[reg] + bn;
        ws_h2[(size_t)(blockIdx.x * 32 + m) * 40 + n] = h;
        ls += h; lq += h * h;
      }
      atomicAdd(&psum[n], ls);
      atomicAdd(&psq[n], lq);
    }
  }
  __syncthreads();
  if (tid < 40) {
    atomicAdd(&g_d2_sum[tid], (double)psum[tid]);
    atomicAdd(&g_d2_sq[tid], (double)psq[tid]);
  }
}

// ---- Kernel 7: dice2(h2), logits, probs, loss -------------------------------
__global__ __launch_bounds__(256) void k7(
    const int* __restrict__ lb,
    const float* __restrict__ d2_alpha, const float* __restrict__ d2_beta,
    const float* __restrict__ d2_gamma, const float* __restrict__ d2_bbeta,
    const float* __restrict__ l3_W, const float* __restrict__ l3_b,
    const float* __restrict__ ws_h2,
    const double* __restrict__ g_d2_sum, const double* __restrict__ g_d2_sq,
    float* __restrict__ out, double* __restrict__ g_loss)
{
  const int tid = threadIdx.x, lane = tid & 63, wv = tid >> 6;
  __shared__ float a2[40], c2[40];
  __shared__ float wls[4];
  if (tid < 40) {
    const double m = g_d2_sum[tid] * (1.0 / (double)NB);
    const double var = g_d2_sq[tid] * (1.0 / (double)NB) - m * m;
    const float rstd = (float)(1.0 / sqrt(var + 1e-8));
    const float g = d2_gamma[tid] * rstd;
    a2[tid] = g; c2[tid] = d2_bbeta[tid] - (float)m * g;
  }
  __syncthreads();

  float wj = 0, b2j = 0, c2j = 0, betaj = 0, alphaj = 0;
  if (lane < 40) {
    wj = l3_W[lane]; b2j = a2[lane]; c2j = c2[lane];
    betaj = d2_beta[lane]; alphaj = d2_alpha[lane];
  }
  const float b3 = l3_b[0];

  float lacc = 0.f;
  for (int r = 0; r < 4; r++) {
    const int row = blockIdx.x * 16 + r * 4 + wv;
    float p = 0.f;
    if (lane < 40) {
      const float v = ws_h2[(size_t)row * 40 + lane];
      const float bn = v * b2j + c2j;
      const float xn = sigm(betaj * bn);
      p = (alphaj * (1.f - xn) * v + xn * v) * wj;
    }
    const float logit = wsum64(p) + b3;
    if (lane == 0) {
      out[row] = 1.f / (1.f + expf(-logit));
      const float lab = (float)lb[row];
      lacc += fmaxf(logit, 0.f) - logit * lab + log1pf(expf(-fabsf(logit)));
    }
  }
  if (lane == 0) wls[wv] = lacc;
  __syncthreads();
  if (tid == 0) atomicAdd(g_loss, (double)(wls[0] + wls[1] + wls[2] + wls[3]));
}

__global__ void k8(const double* __restrict__ g_loss, float* __restrict__ out) {
  out[NB] = (float)(g_loss[0] * (1.0 / (double)NB));
}

} // namespace

extern "C" void kernel_launch(void* const* d_in, const int* in_sizes, int n_in,
                              void* d_out, int out_size, void* d_ws, size_t ws_size,
                              hipStream_t stream) {
  const int* iid       = (const int*)d_in[0];
  const int* aid       = (const int*)d_in[1];
  const int* lb        = (const int*)d_in[2];
  const int* hist_iid  = (const int*)d_in[3];
  const int* hist_aid  = (const int*)d_in[4];
  const int* hist_rate = (const int*)d_in[5];
  const float* item_tab = (const float*)d_in[6];
  const float* cate_tab = (const float*)d_in[7];
  const float* rate_tab = (const float*)d_in[8];
  const float* au_W1    = (const float*)d_in[9];
  const float* au_b1    = (const float*)d_in[10];
  const float* au_alpha = (const float*)d_in[11];
  const float* au_beta  = (const float*)d_in[12];
  const float* au_gamma = (const float*)d_in[13];
  const float* au_bbeta = (const float*)d_in[14];
  const float* au_W2    = (const float*)d_in[15];
  const float* au_b2    = (const float*)d_in[16];
  const float* l1_W     = (const float*)d_in[17];
  const float* l1_b     = (const float*)d_in[18];
  const float* d1_alpha = (const float*)d_in[19];
  const float* d1_beta  = (const float*)d_in[20];
  const float* d1_gamma = (const float*)d_in[21];
  const float* d1_bbeta = (const float*)d_in[22];
  const float* l2_W     = (const float*)d_in[23];
  const float* l2_b     = (const float*)d_in[24];
  const float* d2_alpha = (const float*)d_in[25];
  const float* d2_beta  = (const float*)d_in[26];
  const float* d2_gamma = (const float*)d_in[27];
  const float* d2_bbeta = (const float*)d_in[28];
  const float* l3_W     = (const float*)d_in[29];
  const float* l3_b     = (const float*)d_in[30];
  float* out = (float*)d_out;

  double* g = (double*)d_ws;
  double* g_au_sum = g;
  double* g_au_sq  = g + 36;
  double* g_d1_sum = g + 72;
  double* g_d1_sq  = g + 152;
  double* g_d2_sum = g + 232;
  double* g_d2_sq  = g + 272;
  double* g_loss   = g + 312;
  float* fbase  = (float*)((char*)d_ws + 4096);
  float* ws_y   = fbase;                       // NB*180
  float* ws_w   = fbase + (size_t)NB * 180;    // NB*5
  float* ws_h1  = fbase + (size_t)NB * 185;    // NB*80
  float* ws_h2  = fbase + (size_t)NB * 265;    // NB*40
  int*   ws_hi  = (int*)(fbase + (size_t)NB * 305);  // NB*5
  int*   ws_ha  = ws_hi + (size_t)NB * NK;
  int*   ws_hr  = ws_ha + (size_t)NB * NK;

  hipMemsetAsync(d_ws, 0, 313 * sizeof(double), stream);
  k1<<<dim3(NB / 8), 512, 0, stream>>>(iid, aid, hist_iid, hist_aid, hist_rate,
                              item_tab, cate_tab, au_W1, au_b1,
                              ws_y, ws_w, ws_hi, ws_ha, ws_hr, g_au_sum, g_au_sq);
  k3<<<dim3(NB / 32), 512, 0, stream>>>(iid, aid, item_tab, cate_tab, rate_tab,
                              au_alpha, au_beta, au_gamma, au_bbeta, au_W2, au_b2,
                              l1_W, l1_b, ws_y, ws_w, ws_hi, ws_ha, ws_hr,
                              g_au_sum, g_au_sq, ws_h1, g_d1_sum, g_d1_sq);
  k5<<<dim3(NB / 32), 512, 0, stream>>>(d1_alpha, d1_beta, d1_gamma, d1_bbeta, l2_W, l2_b,
                              ws_h1, g_d1_sum, g_d1_sq, ws_h2, g_d2_sum, g_d2_sq);
  k7<<<dim3(NB / 16), 256, 0, stream>>>(lb, d2_alpha, d2_beta, d2_gamma, d2_bbeta, l3_W, l3_b,
                              ws_h2, g_d2_sum, g_d2_sq, out, g_loss);
  k8<<<1, 1, 0, stream>>>(g_loss, out);
}

// Round 9
// 189.936 us; speedup vs baseline: 1.6136x; 1.0001x over previous
//
#include <hip/hip_runtime.h>
#include <cmath>

namespace {
constexpr int NB = 16384;
constexpr int NS = 50;
constexpr int NK = 5;
constexpr int NH = 32;

// sharded f64 stat layout (8 shards x 312 doubles) + loss + counter
constexpr int AU_SUM = 0, AU_SQ = 36, D1_SUM = 72, D1_SQ = 152, D2_SUM = 232, D2_SQ = 272;
constexpr int SHARD_STRIDE = 312;
constexpr int NSHARD = 8;
constexpr int LOSS_OFF = SHARD_STRIDE * NSHARD;      // 2496
constexpr int CNT_OFF  = LOSS_OFF + 1;               // 2497 (as int storage)

typedef __attribute__((ext_vector_type(8))) short bf16x8;
typedef __attribute__((ext_vector_type(4))) float f32x4;

__device__ __forceinline__ float wsum64(float v) {
#pragma unroll
  for (int off = 32; off; off >>= 1) v += __shfl_xor(v, off, 64);
  return v;
}

__device__ __forceinline__ float sigm(float x) { return 1.0f / (1.0f + expf(-x)); }

__device__ __forceinline__ unsigned short f2bf(float f) {
  union { float f; unsigned u; } v; v.f = f;
  unsigned r = v.u + 0x7fffu + ((v.u >> 16) & 1u);
  return (unsigned short)(r >> 16);
}

// ---- Kernel 1: embeddings, sim, top-5, x @ au_W1 via MFMA, au-BN stats ------
// 512 thr = 8 waves; 16 rows/block (grid 1024); each wave owns 2 rows whose
// chains are INTERLEAVED in registers (per-row arithmetic bit-identical to R6).
__global__ __launch_bounds__(512) void k1(
    const int* __restrict__ iid, const int* __restrict__ aid,
    const int* __restrict__ hist_iid, const int* __restrict__ hist_aid,
    const int* __restrict__ hist_rate,
    const float* __restrict__ item_tab, const float* __restrict__ cate_tab,
    const float* __restrict__ au_W1, const float* __restrict__ au_b1,
    float* __restrict__ ws_y, float* __restrict__ ws_w,
    int* __restrict__ ws_hi, int* __restrict__ ws_ha, int* __restrict__ ws_hr,
    double* __restrict__ gstats)
{
  const int tid = threadIdx.x;
  const int lane = tid & 63;
  const int wv = tid >> 6;
  const int shard = blockIdx.x & (NSHARD - 1);

  __shared__ alignas(16) unsigned short w1t[48][136];
  __shared__ alignas(16) unsigned short xb[80][136];
  __shared__ float icsh[2][8][64];
  __shared__ float crossm[80];
  __shared__ float w1c[36], b1s[36];
  __shared__ float psum[36], psq[36];

  for (int e = tid; e < 48 * 136; e += 512) {
    const int n = e / 136, k = e - 136 * n;
    float v = 0.f;
    if (n < 36 && k < 128) {
      const int i = (k < 64) ? k : (k + 1);
      v = au_W1[i * 36 + n];
    }
    w1t[n][k] = f2bf(v);
  }
  if (tid < 36) {
    w1c[tid] = au_W1[64 * 36 + tid];
    b1s[tid] = au_b1[tid];
    psum[tid] = 0.f; psq[tid] = 0.f;
  }

  int rowr[2];
  float icr[2], n1r[2];
  int hi[2], ha[2], rv[2];
  float dotv[2], sim[2], n2sq[2];

#pragma unroll
  for (int r = 0; r < 2; r++) {
    rowr[r] = blockIdx.x * 16 + r * 8 + wv;
    const int iv = iid[rowr[r]];
    const int cv = aid[rowr[r]];
    icr[r] = (lane < 32) ? item_tab[iv * NH + lane] : cate_tab[cv * NH + lane - 32];
    icsh[r][wv][lane] = icr[r];
  }
#pragma unroll
  for (int r = 0; r < 2; r++) n1r[r] = sqrtf(wsum64(icr[r] * icr[r]));

#pragma unroll
  for (int r = 0; r < 2; r++) {
    hi[r] = 0; ha[r] = 0; rv[r] = 0;
    dotv[r] = 0.f; sim[r] = -INFINITY; n2sq[r] = 0.f;
    if (lane < NS) {
      hi[r] = hist_iid[rowr[r] * NS + lane];
      ha[r] = hist_aid[rowr[r] * NS + lane];
      rv[r] = hist_rate[rowr[r] * NS + lane];
    }
  }

  if (lane < NS) {
    // item table pass (q interleaved across rows; per-row order identical to R6)
#pragma unroll
    for (int q = 0; q < 8; q++) {
#pragma unroll
      for (int r = 0; r < 2; r++) {
        const float4* ip = reinterpret_cast<const float4*>(item_tab + (size_t)hi[r] * NH);
        const float* ics = icsh[r][wv];
        float4 a = ip[q];
        dotv[r] += ics[4*q+0]*a.x + ics[4*q+1]*a.y + ics[4*q+2]*a.z + ics[4*q+3]*a.w;
        n2sq[r] += a.x*a.x + a.y*a.y + a.z*a.z + a.w*a.w;
      }
    }
#pragma unroll
    for (int q = 0; q < 8; q++) {
#pragma unroll
      for (int r = 0; r < 2; r++) {
        const float4* cp = reinterpret_cast<const float4*>(cate_tab + (size_t)ha[r] * NH);
        const float* ics = icsh[r][wv];
        float4 a = cp[q];
        dotv[r] += ics[32+4*q+0]*a.x + ics[32+4*q+1]*a.y + ics[32+4*q+2]*a.z + ics[32+4*q+3]*a.w;
        n2sq[r] += a.x*a.x + a.y*a.y + a.z*a.z + a.w*a.w;
      }
    }
#pragma unroll
    for (int r = 0; r < 2; r++)
      sim[r] = dotv[r] / fmaxf(n1r[r] * sqrtf(n2sq[r]), 1e-8f);
  }

  // top-5 interleaved: per-row compare/shfl sequence identical to R6
  float simw[2] = { sim[0], sim[1] };
  const int si = (lane < NS) ? lane : 1000;
  float vals[2][NK]; int idxs[2][NK];
#pragma unroll
  for (int rr = 0; rr < NK; rr++) {
    float v[2]; int ii[2];
#pragma unroll
    for (int r = 0; r < 2; r++) { v[r] = simw[r]; ii[r] = si; }
#pragma unroll
    for (int off = 32; off; off >>= 1) {
#pragma unroll
      for (int r = 0; r < 2; r++) {
        float ov = __shfl_xor(v[r], off, 64);
        int   oi = __shfl_xor(ii[r], off, 64);
        if (ov > v[r] || (ov == v[r] && oi < ii[r])) { v[r] = ov; ii[r] = oi; }
      }
    }
#pragma unroll
    for (int r = 0; r < 2; r++) {
      vals[r][rr] = v[r]; idxs[r][rr] = ii[r];
      if (si == ii[r]) simw[r] = -INFINITY;
    }
  }

  float ssumw[2];
#pragma unroll
  for (int r = 0; r < 2; r++)
    ssumw[r] = vals[r][0] + vals[r][1] + vals[r][2] + vals[r][3] + vals[r][4] + 1e-8f;

#pragma unroll
  for (int k = 0; k < NK; k++) {
#pragma unroll
    for (int r = 0; r < 2; r++) {
      const float wk = vals[r][k] / ssumw[r];
      const float crossk = wk * __shfl(dotv[r], idxs[r][k], 64);
      const int hik = __shfl(hi[r], idxs[r][k], 64);
      const int hak = __shfl(ha[r], idxs[r][k], 64);
      const int rvk = __shfl(rv[r], idxs[r][k], 64);
      const float e = (lane < 32) ? item_tab[hik * NH + lane] : cate_tab[hak * NH + lane - 32];
      const int m = (r * 8 + wv) * 5 + k;
      xb[m][lane] = f2bf(wk * e);
      xb[m][64 + lane] = f2bf(icr[r]);
      if (lane == 0) crossm[m] = crossk;
      if (lane == k) {
        ws_w[rowr[r] * NK + k] = wk;
        ws_hi[rowr[r] * NK + k] = hik;
        ws_ha[rowr[r] * NK + k] = hak;
        ws_hr[rowr[r] * NK + k] = rvk;
      }
    }
  }
  __syncthreads();

  // MFMA GEMM: M=80 (5 tiles), N=36->48 (3 tiles), K=128 (4 steps)
  const int l15 = lane & 15, lhi = lane >> 4;
  for (int t = wv; t < 15; t += 8) {
    const int mt = t / 3, nt = t - 3 * mt;
    f32x4 acc = {0.f, 0.f, 0.f, 0.f};
#pragma unroll
    for (int ks = 0; ks < 4; ks++) {
      const int k0 = ks * 32 + lhi * 8;
      const bf16x8 a = *reinterpret_cast<const bf16x8*>(&xb[mt * 16 + l15][k0]);
      const bf16x8 b = *reinterpret_cast<const bf16x8*>(&w1t[nt * 16 + l15][k0]);
      acc = __builtin_amdgcn_mfma_f32_16x16x32_bf16(a, b, acc, 0, 0, 0);
    }
    const int n = nt * 16 + l15;
    if (n < 36) {
      const float w1cn = w1c[n], b1n = b1s[n];
      float ls = 0.f, lq = 0.f;
#pragma unroll
      for (int reg = 0; reg < 4; reg++) {
        const int m = mt * 16 + 4 * lhi + reg;
        const float y = acc[reg] + b1n + crossm[m] * w1cn;
        ws_y[(size_t)(blockIdx.x * 80 + m) * 36 + n] = y;
        ls += y; lq += y * y;
      }
      atomicAdd(&psum[n], ls);
      atomicAdd(&psq[n], lq);
    }
  }
  __syncthreads();
  if (tid < 36) {
    atomicAdd(&gstats[shard * SHARD_STRIDE + AU_SUM + tid], (double)psum[tid]);
    atomicAdd(&gstats[shard * SHARD_STRIDE + AU_SQ + tid], (double)psq[tid]);
  }
}

// ---- Kernel 3: dice3 (LDS-staged aout), final_hist, res @ l1_W, d1 stats ----
__global__ __launch_bounds__(512) void k3(
    const int* __restrict__ iid, const int* __restrict__ aid,
    const float* __restrict__ item_tab, const float* __restrict__ cate_tab,
    const float* __restrict__ rate_tab,
    const float* __restrict__ au_alpha, const float* __restrict__ au_beta,
    const float* __restrict__ au_gamma, const float* __restrict__ au_bbeta,
    const float* __restrict__ au_W2, const float* __restrict__ au_b2,
    const float* __restrict__ l1_W, const float* __restrict__ l1_b,
    const float* __restrict__ ws_y, const float* __restrict__ ws_w,
    const int* __restrict__ ws_hi, const int* __restrict__ ws_ha,
    const int* __restrict__ ws_hr,
    double* __restrict__ gstats,
    float* __restrict__ ws_h1)
{
  const int tid = threadIdx.x, lane = tid & 63, wv = tid >> 6;
  const int base = blockIdx.x * 32;
  const int shard = blockIdx.x & (NSHARD - 1);
  __shared__ alignas(16) unsigned short l1t[80][168];
  __shared__ alignas(16) unsigned short resb[32][168];
  __shared__ float ysh[160][37];
  __shared__ float aoutsh[160];
  __shared__ float asc[36], bsc[36], bets[36], alps[36], w2s[36];
  __shared__ float psum[80], psq[80];

  for (int e = tid; e < 80 * 168; e += 512) {
    const int n = e / 168, k = e - 168 * n;
    l1t[n][k] = (k < 160) ? f2bf(l1_W[k * 80 + n]) : (unsigned short)0;
  }
  for (int e = tid; e < 160 * 36; e += 512) {
    ysh[e / 36][e % 36] = ws_y[(size_t)base * 180 + e];
  }
  if (tid < 36) {
    double s = 0.0, q = 0.0;
#pragma unroll
    for (int sh = 0; sh < NSHARD; sh++) {
      s += gstats[sh * SHARD_STRIDE + AU_SUM + tid];
      q += gstats[sh * SHARD_STRIDE + AU_SQ + tid];
    }
    const double m = s * (1.0 / ((double)NB * NK));
    const double var = q * (1.0 / ((double)NB * NK)) - m * m;
    const float rstd = (float)(1.0 / sqrt(var + 1e-8));
    const float g = au_gamma[tid] * rstd;
    asc[tid] = g; bsc[tid] = au_bbeta[tid] - (float)m * g;
    bets[tid] = au_beta[tid];
    alps[tid] = au_alpha[tid];
    w2s[tid] = au_W2[tid];
  }
  if (tid < 80) { psum[tid] = 0.f; psq[tid] = 0.f; }
  __syncthreads();

  const float bias2 = au_b2[0];
  if (tid < 160) {
    float acc = 0.f;
#pragma unroll
    for (int j = 0; j < 36; j++) {
      const float yv = ysh[tid][j];
      const float bn = yv * asc[j] + bsc[j];
      const float xn = sigm(bets[j] * bn);
      acc = fmaf(alps[j] * (1.f - xn) * yv + xn * yv, w2s[j], acc);
    }
    aoutsh[tid] = acc + bias2;
  }
  __syncthreads();

  for (int r = 0; r < 4; r++) {
    const int lm = r * 8 + wv;
    const int row = base + lm;
    const int iv = iid[row], cv = aid[row];
    const float ic = (lane < 32) ? item_tab[iv * NH + lane] : cate_tab[cv * NH + lane - 32];
    float fh0 = 0.f, fh1 = 0.f;
#pragma unroll
    for (int k = 0; k < NK; k++) {
      const int hik = ws_hi[row * NK + k];
      const int hak = ws_ha[row * NK + k];
      const int rvk = ws_hr[row * NK + k];
      const float wk = ws_w[row * NK + k];
      const float aok = aoutsh[lm * 5 + k];
      const float e = (lane < 32) ? item_tab[hik * NH + lane] : cate_tab[hak * NH + lane - 32];
      fh0 = fmaf(wk * e, aok, fh0);
      if (lane < 32) fh1 = fmaf(rate_tab[rvk * NH + lane], aok, fh1);
    }
    resb[lm][lane] = f2bf(ic);
    resb[lm][64 + lane] = f2bf(fh0);
    if (lane < 32) resb[lm][128 + lane] = f2bf(fh1);
  }
  __syncthreads();

  const int l15 = lane & 15, lhi = lane >> 4;
  for (int t = wv; t < 10; t += 8) {
    const int mt = t / 5, nt = t - 5 * mt;
    f32x4 acc = {0.f, 0.f, 0.f, 0.f};
#pragma unroll
    for (int ks = 0; ks < 5; ks++) {
      const int k0 = ks * 32 + lhi * 8;
      const bf16x8 a = *reinterpret_cast<const bf16x8*>(&resb[mt * 16 + l15][k0]);
      const bf16x8 b = *reinterpret_cast<const bf16x8*>(&l1t[nt * 16 + l15][k0]);
      acc = __builtin_amdgcn_mfma_f32_16x16x32_bf16(a, b, acc, 0, 0, 0);
    }
    const int n = nt * 16 + l15;
    const float bn = l1_b[n];
    float ls = 0.f, lq = 0.f;
#pragma unroll
    for (int reg = 0; reg < 4; reg++) {
      const int m = mt * 16 + 4 * lhi + reg;
      const float h = acc[reg] + bn;
      ws_h1[(size_t)(base + m) * 80 + n] = h;
      ls += h; lq += h * h;
    }
    atomicAdd(&psum[n], ls);
    atomicAdd(&psq[n], lq);
  }
  __syncthreads();
  if (tid < 80) {
    atomicAdd(&gstats[shard * SHARD_STRIDE + D1_SUM + tid], (double)psum[tid]);
    atomicAdd(&gstats[shard * SHARD_STRIDE + D1_SQ + tid], (double)psq[tid]);
  }
}

// ---- Kernel 5: dice2(h1), h @ l2_W via MFMA, d2 stats -----------------------
__global__ __launch_bounds__(512) void k5(
    const float* __restrict__ d1_alpha, const float* __restrict__ d1_beta,
    const float* __restrict__ d1_gamma, const float* __restrict__ d1_bbeta,
    const float* __restrict__ l2_W, const float* __restrict__ l2_b,
    const float* __restrict__ ws_h1,
    double* __restrict__ gstats,
    float* __restrict__ ws_h2)
{
  const int tid = threadIdx.x, lane = tid & 63, wv = tid >> 6;
  const int shard = blockIdx.x & (NSHARD - 1);
  __shared__ alignas(16) unsigned short l2t[48][104];
  __shared__ alignas(16) unsigned short h1b[32][104];
  __shared__ float a1[80], c1[80];
  __shared__ float psum[40], psq[40];

  for (int e = tid; e < 48 * 104; e += 512) {
    const int n = e / 104, k = e - 104 * n;
    l2t[n][k] = (n < 40 && k < 80) ? f2bf(l2_W[k * 40 + n]) : (unsigned short)0;
  }
  if (tid < 80) {
    double s = 0.0, q = 0.0;
#pragma unroll
    for (int sh = 0; sh < NSHARD; sh++) {
      s += gstats[sh * SHARD_STRIDE + D1_SUM + tid];
      q += gstats[sh * SHARD_STRIDE + D1_SQ + tid];
    }
    const double m = s * (1.0 / (double)NB);
    const double var = q * (1.0 / (double)NB) - m * m;
    const float rstd = (float)(1.0 / sqrt(var + 1e-8));
    const float g = d1_gamma[tid] * rstd;
    a1[tid] = g; c1[tid] = d1_bbeta[tid] - (float)m * g;
  }
  if (tid < 40) { psum[tid] = 0.f; psq[tid] = 0.f; }
  __syncthreads();

  for (int r = 0; r < 4; r++) {
    const int lm = r * 8 + wv;
    const int row = blockIdx.x * 32 + lm;
    {
      const float v = ws_h1[(size_t)row * 80 + lane];
      const float bn = v * a1[lane] + c1[lane];
      const float xn = sigm(d1_beta[lane] * bn);
      h1b[lm][lane] = f2bf(d1_alpha[lane] * (1.f - xn) * v + xn * v);
    }
    const int o = 64 + lane;
    if (lane < 16) {
      const float v = ws_h1[(size_t)row * 80 + o];
      const float bn = v * a1[o] + c1[o];
      const float xn = sigm(d1_beta[o] * bn);
      h1b[lm][o] = f2bf(d1_alpha[o] * (1.f - xn) * v + xn * v);
    } else if (lane < 32) {
      h1b[lm][o] = 0;
    }
  }
  __syncthreads();

  const int l15 = lane & 15, lhi = lane >> 4;
  for (int t = wv; t < 6; t += 8) {
    const int mt = t / 3, nt = t - 3 * mt;
    f32x4 acc = {0.f, 0.f, 0.f, 0.f};
#pragma unroll
    for (int ks = 0; ks < 3; ks++) {
      const int k0 = ks * 32 + lhi * 8;
      const bf16x8 a = *reinterpret_cast<const bf16x8*>(&h1b[mt * 16 + l15][k0]);
      const bf16x8 b = *reinterpret_cast<const bf16x8*>(&l2t[nt * 16 + l15][k0]);
      acc = __builtin_amdgcn_mfma_f32_16x16x32_bf16(a, b, acc, 0, 0, 0);
    }
    const int n = nt * 16 + l15;
    if (n < 40) {
      const float bn = l2_b[n];
      float ls = 0.f, lq = 0.f;
#pragma unroll
      for (int reg = 0; reg < 4; reg++) {
        const int m = mt * 16 + 4 * lhi + reg;
        const float h = acc[reg] + bn;
        ws_h2[(size_t)(blockIdx.x * 32 + m) * 40 + n] = h;
        ls += h; lq += h * h;
      }
      atomicAdd(&psum[n], ls);
      atomicAdd(&psq[n], lq);
    }
  }
  __syncthreads();
  if (tid < 40) {
    atomicAdd(&gstats[shard * SHARD_STRIDE + D2_SUM + tid], (double)psum[tid]);
    atomicAdd(&gstats[shard * SHARD_STRIDE + D2_SQ + tid], (double)psq[tid]);
  }
}

// ---- Kernel 7: dice2(h2), logits, probs, loss (+ last-block finalize) -------
__global__ __launch_bounds__(256) void k7(
    const int* __restrict__ lb,
    const float* __restrict__ d2_alpha, const float* __restrict__ d2_beta,
    const float* __restrict__ d2_gamma, const float* __restrict__ d2_bbeta,
    const float* __restrict__ l3_W, const float* __restrict__ l3_b,
    const float* __restrict__ ws_h2,
    double* __restrict__ gstats,
    float* __restrict__ out)
{
  const int tid = threadIdx.x, lane = tid & 63, wv = tid >> 6;
  __shared__ float a2[40], c2[40];
  __shared__ float wls[4];
  if (tid < 40) {
    double s = 0.0, q = 0.0;
#pragma unroll
    for (int sh = 0; sh < NSHARD; sh++) {
      s += gstats[sh * SHARD_STRIDE + D2_SUM + tid];
      q += gstats[sh * SHARD_STRIDE + D2_SQ + tid];
    }
    const double m = s * (1.0 / (double)NB);
    const double var = q * (1.0 / (double)NB) - m * m;
    const float rstd = (float)(1.0 / sqrt(var + 1e-8));
    const float g = d2_gamma[tid] * rstd;
    a2[tid] = g; c2[tid] = d2_bbeta[tid] - (float)m * g;
  }
  __syncthreads();

  float wj = 0, b2j = 0, c2j = 0, betaj = 0, alphaj = 0;
  if (lane < 40) {
    wj = l3_W[lane]; b2j = a2[lane]; c2j = c2[lane];
    betaj = d2_beta[lane]; alphaj = d2_alpha[lane];
  }
  const float b3 = l3_b[0];

  float lacc = 0.f;
  for (int r = 0; r < 4; r++) {
    const int row = blockIdx.x * 16 + r * 4 + wv;
    float p = 0.f;
    if (lane < 40) {
      const float v = ws_h2[(size_t)row * 40 + lane];
      const float bn = v * b2j + c2j;
      const float xn = sigm(betaj * bn);
      p = (alphaj * (1.f - xn) * v + xn * v) * wj;
    }
    const float logit = wsum64(p) + b3;
    if (lane == 0) {
      out[row] = 1.f / (1.f + expf(-logit));
      const float lab = (float)lb[row];
      lacc += fmaxf(logit, 0.f) - logit * lab + log1pf(expf(-fabsf(logit)));
    }
  }
  if (lane == 0) wls[wv] = lacc;
  __syncthreads();
  if (tid == 0) {
    double* g_loss = gstats + LOSS_OFF;
    unsigned int* g_cnt = (unsigned int*)(gstats + CNT_OFF);
    atomicAdd(g_loss, (double)(wls[0] + wls[1] + wls[2] + wls[3]));
    __threadfence();
    const unsigned prev = atomicAdd(g_cnt, 1u);
    if (prev == (unsigned)(gridDim.x - 1)) {
      const double tot = atomicAdd(g_loss, 0.0);
      out[NB] = (float)(tot * (1.0 / (double)NB));
    }
  }
}

} // namespace

extern "C" void kernel_launch(void* const* d_in, const int* in_sizes, int n_in,
                              void* d_out, int out_size, void* d_ws, size_t ws_size,
                              hipStream_t stream) {
  const int* iid       = (const int*)d_in[0];
  const int* aid       = (const int*)d_in[1];
  const int* lb        = (const int*)d_in[2];
  const int* hist_iid  = (const int*)d_in[3];
  const int* hist_aid  = (const int*)d_in[4];
  const int* hist_rate = (const int*)d_in[5];
  const float* item_tab = (const float*)d_in[6];
  const float* cate_tab = (const float*)d_in[7];
  const float* rate_tab = (const float*)d_in[8];
  const float* au_W1    = (const float*)d_in[9];
  const float* au_b1    = (const float*)d_in[10];
  const float* au_alpha = (const float*)d_in[11];
  const float* au_beta  = (const float*)d_in[12];
  const float* au_gamma = (const float*)d_in[13];
  const float* au_bbeta = (const float*)d_in[14];
  const float* au_W2    = (const float*)d_in[15];
  const float* au_b2    = (const float*)d_in[16];
  const float* l1_W     = (const float*)d_in[17];
  const float* l1_b     = (const float*)d_in[18];
  const float* d1_alpha = (const float*)d_in[19];
  const float* d1_beta  = (const float*)d_in[20];
  const float* d1_gamma = (const float*)d_in[21];
  const float* d1_bbeta = (const float*)d_in[22];
  const float* l2_W     = (const float*)d_in[23];
  const float* l2_b     = (const float*)d_in[24];
  const float* d2_alpha = (const float*)d_in[25];
  const float* d2_beta  = (const float*)d_in[26];
  const float* d2_gamma = (const float*)d_in[27];
  const float* d2_bbeta = (const float*)d_in[28];
  const float* l3_W     = (const float*)d_in[29];
  const float* l3_b     = (const float*)d_in[30];
  float* out = (float*)d_out;

  double* gstats = (double*)d_ws;
  float* fbase  = (float*)((char*)d_ws + 32768);
  float* ws_y   = fbase;                       // NB*180
  float* ws_w   = fbase + (size_t)NB * 180;    // NB*5
  float* ws_h1  = fbase + (size_t)NB * 185;    // NB*80
  float* ws_h2  = fbase + (size_t)NB * 265;    // NB*40
  int*   ws_hi  = (int*)(fbase + (size_t)NB * 305);  // NB*5
  int*   ws_ha  = ws_hi + (size_t)NB * NK;
  int*   ws_hr  = ws_ha + (size_t)NB * NK;

  hipMemsetAsync(d_ws, 0, (CNT_OFF + 2) * sizeof(double), stream);
  k1<<<dim3(NB / 16), 512, 0, stream>>>(iid, aid, hist_iid, hist_aid, hist_rate,
                              item_tab, cate_tab, au_W1, au_b1,
                              ws_y, ws_w, ws_hi, ws_ha, ws_hr, gstats);
  k3<<<dim3(NB / 32), 512, 0, stream>>>(iid, aid, item_tab, cate_tab, rate_tab,
                              au_alpha, au_beta, au_gamma, au_bbeta, au_W2, au_b2,
                              l1_W, l1_b, ws_y, ws_w, ws_hi, ws_ha, ws_hr,
                              gstats, ws_h1);
  k5<<<dim3(NB / 32), 512, 0, stream>>>(d1_alpha, d1_beta, d1_gamma, d1_bbeta, l2_W, l2_b,
                              ws_h1, gstats, ws_h2);
  k7<<<dim3(NB / 16), 256, 0, stream>>>(lb, d2_alpha, d2_beta, d2_gamma, d2_bbeta, l3_W, l3_b,
                              ws_h2, gstats, out);
}

// Round 10
// 157.948 us; speedup vs baseline: 1.9403x; 1.2025x over previous
//
#include <hip/hip_runtime.h>
#include <cmath>

namespace {
constexpr int NB = 16384;
constexpr int NS = 50;
constexpr int NK = 5;
constexpr int NH = 32;

// sharded f64 stat layout (8 shards x 312 doubles) + loss + counter
constexpr int AU_SUM = 0, AU_SQ = 36, D1_SUM = 72, D1_SQ = 152, D2_SUM = 232, D2_SQ = 272;
constexpr int SHARD_STRIDE = 312;
constexpr int NSHARD = 8;
constexpr int LOSS_OFF = SHARD_STRIDE * NSHARD;      // 2496
constexpr int CNT_OFF  = LOSS_OFF + 1;               // 2497 (as int storage)

typedef __attribute__((ext_vector_type(8))) short bf16x8;
typedef __attribute__((ext_vector_type(4))) float f32x4;

__device__ __forceinline__ float wsum64(float v) {
#pragma unroll
  for (int off = 32; off; off >>= 1) v += __shfl_xor(v, off, 64);
  return v;
}

__device__ __forceinline__ float sigm(float x) { return 1.0f / (1.0f + expf(-x)); }

__device__ __forceinline__ unsigned short f2bf(float f) {
  union { float f; unsigned u; } v; v.f = f;
  unsigned r = v.u + 0x7fffu + ((v.u >> 16) & 1u);
  return (unsigned short)(r >> 16);
}

// ---- Kernel 1: embeddings, sim, top-5, x @ au_W1 via MFMA, au-BN stats ------
// 512 thr = 8 waves; 16 rows/block, 2 serial rows per wave (R6 structure,
// VGPR<=64). Sims/dotv: R6-verbatim per-lane sequential sums (bit-identical).
// Top-5 via rank (independent shfl broadcasts) — selection-exact vs top_k.
__global__ __launch_bounds__(512) void k1(
    const int* __restrict__ iid, const int* __restrict__ aid,
    const int* __restrict__ hist_iid, const int* __restrict__ hist_aid,
    const int* __restrict__ hist_rate,
    const float* __restrict__ item_tab, const float* __restrict__ cate_tab,
    const float* __restrict__ au_W1, const float* __restrict__ au_b1,
    float* __restrict__ ws_y, float* __restrict__ ws_w,
    int* __restrict__ ws_hi, int* __restrict__ ws_ha, int* __restrict__ ws_hr,
    double* __restrict__ gstats)
{
  const int tid = threadIdx.x;
  const int lane = tid & 63;
  const int wv = tid >> 6;
  const int shard = blockIdx.x & (NSHARD - 1);

  __shared__ alignas(16) unsigned short w1t[48][136];
  __shared__ alignas(16) unsigned short xb[80][136];
  __shared__ float icsh[8][64];
  __shared__ float crossm[80];
  __shared__ float w1c[36], b1s[36];
  __shared__ float psum[36], psq[36];

  for (int e = tid; e < 48 * 136; e += 512) {
    const int n = e / 136, k = e - 136 * n;
    float v = 0.f;
    if (n < 36 && k < 128) {
      const int i = (k < 64) ? k : (k + 1);
      v = au_W1[i * 36 + n];
    }
    w1t[n][k] = f2bf(v);
  }
  if (tid < 36) {
    w1c[tid] = au_W1[64 * 36 + tid];
    b1s[tid] = au_b1[tid];
    psum[tid] = 0.f; psq[tid] = 0.f;
  }

  for (int r = 0; r < 2; r++) {
    const int lm = r * 8 + wv;
    const int row = blockIdx.x * 16 + lm;

    const int iv = iid[row];
    const int cv = aid[row];
    const float ic = (lane < 32) ? item_tab[iv * NH + lane] : cate_tab[cv * NH + lane - 32];
    icsh[wv][lane] = ic;
    const float n1 = sqrtf(wsum64(ic * ic));

    int hi = 0, ha = 0, rv = 0;
    float dotv = 0.f, sim = -INFINITY;
    if (lane < NS) {
      hi = hist_iid[row * NS + lane];
      ha = hist_aid[row * NS + lane];
      rv = hist_rate[row * NS + lane];
      const float4* ip = reinterpret_cast<const float4*>(item_tab + (size_t)hi * NH);
      const float4* cp = reinterpret_cast<const float4*>(cate_tab + (size_t)ha * NH);
      const float* ics = icsh[wv];
      float n2sq = 0.f;
#pragma unroll
      for (int q = 0; q < 8; q++) {
        float4 a = ip[q];
        dotv += ics[4*q+0]*a.x + ics[4*q+1]*a.y + ics[4*q+2]*a.z + ics[4*q+3]*a.w;
        n2sq += a.x*a.x + a.y*a.y + a.z*a.z + a.w*a.w;
      }
#pragma unroll
      for (int q = 0; q < 8; q++) {
        float4 a = cp[q];
        dotv += ics[32+4*q+0]*a.x + ics[32+4*q+1]*a.y + ics[32+4*q+2]*a.z + ics[32+4*q+3]*a.w;
        n2sq += a.x*a.x + a.y*a.y + a.z*a.z + a.w*a.w;
      }
      sim = dotv / fmaxf(n1 * sqrtf(n2sq), 1e-8f);
    }

    // rank-based top-5: desc value, asc index (== jax.lax.top_k) given
    // bit-identical sims. 50 independent broadcasts, no dependent chain.
    int rank = 0;
#pragma unroll
    for (int j = 0; j < NS; j++) {
      const float sj = __shfl(sim, j, 64);
      rank += (sj > sim) || (sj == sim && j < lane);
    }
    int tk[NK]; float vals[NK];
#pragma unroll
    for (int k = 0; k < NK; k++) {
      const unsigned long long mk = __ballot((lane < NS) && (rank == k));
      tk[k] = __ffsll((long long)mk) - 1;
    }
#pragma unroll
    for (int k = 0; k < NK; k++) vals[k] = __shfl(sim, tk[k], 64);

    const float ssumw = vals[0] + vals[1] + vals[2] + vals[3] + vals[4] + 1e-8f;
#pragma unroll
    for (int k = 0; k < NK; k++) {
      const float wk = vals[k] / ssumw;
      const float crossk = wk * __shfl(dotv, tk[k], 64);
      const int hik = __shfl(hi, tk[k], 64);
      const int hak = __shfl(ha, tk[k], 64);
      const int rvk = __shfl(rv, tk[k], 64);
      const float e = (lane < 32) ? item_tab[hik * NH + lane] : cate_tab[hak * NH + lane - 32];
      const int m = lm * 5 + k;
      xb[m][lane] = f2bf(wk * e);
      xb[m][64 + lane] = f2bf(ic);
      if (lane == 0) crossm[m] = crossk;
      if (lane == k) {
        ws_w[row * NK + k] = wk;
        ws_hi[row * NK + k] = hik;
        ws_ha[row * NK + k] = hak;
        ws_hr[row * NK + k] = rvk;
      }
    }
  }
  __syncthreads();

  // MFMA GEMM: M=80 (5 tiles), N=36->48 (3 tiles), K=128 (4 steps)
  const int l15 = lane & 15, lhi = lane >> 4;
  for (int t = wv; t < 15; t += 8) {
    const int mt = t / 3, nt = t - 3 * mt;
    f32x4 acc = {0.f, 0.f, 0.f, 0.f};
#pragma unroll
    for (int ks = 0; ks < 4; ks++) {
      const int k0 = ks * 32 + lhi * 8;
      const bf16x8 a = *reinterpret_cast<const bf16x8*>(&xb[mt * 16 + l15][k0]);
      const bf16x8 b = *reinterpret_cast<const bf16x8*>(&w1t[nt * 16 + l15][k0]);
      acc = __builtin_amdgcn_mfma_f32_16x16x32_bf16(a, b, acc, 0, 0, 0);
    }
    const int n = nt * 16 + l15;
    if (n < 36) {
      const float w1cn = w1c[n], b1n = b1s[n];
      float ls = 0.f, lq = 0.f;
#pragma unroll
      for (int reg = 0; reg < 4; reg++) {
        const int m = mt * 16 + 4 * lhi + reg;
        const float y = acc[reg] + b1n + crossm[m] * w1cn;
        ws_y[(size_t)(blockIdx.x * 80 + m) * 36 + n] = y;
        ls += y; lq += y * y;
      }
      atomicAdd(&psum[n], ls);
      atomicAdd(&psq[n], lq);
    }
  }
  __syncthreads();
  if (tid < 36) {
    atomicAdd(&gstats[shard * SHARD_STRIDE + AU_SUM + tid], (double)psum[tid]);
    atomicAdd(&gstats[shard * SHARD_STRIDE + AU_SQ + tid], (double)psq[tid]);
  }
}

// ---- Kernel 3: dice3 (LDS-staged aout), final_hist, res @ l1_W, d1 stats ----
__global__ __launch_bounds__(512) void k3(
    const int* __restrict__ iid, const int* __restrict__ aid,
    const float* __restrict__ item_tab, const float* __restrict__ cate_tab,
    const float* __restrict__ rate_tab,
    const float* __restrict__ au_alpha, const float* __restrict__ au_beta,
    const float* __restrict__ au_gamma, const float* __restrict__ au_bbeta,
    const float* __restrict__ au_W2, const float* __restrict__ au_b2,
    const float* __restrict__ l1_W, const float* __restrict__ l1_b,
    const float* __restrict__ ws_y, const float* __restrict__ ws_w,
    const int* __restrict__ ws_hi, const int* __restrict__ ws_ha,
    const int* __restrict__ ws_hr,
    double* __restrict__ gstats,
    float* __restrict__ ws_h1)
{
  const int tid = threadIdx.x, lane = tid & 63, wv = tid >> 6;
  const int base = blockIdx.x * 32;
  const int shard = blockIdx.x & (NSHARD - 1);
  __shared__ alignas(16) unsigned short l1t[80][168];
  __shared__ alignas(16) unsigned short resb[32][168];
  __shared__ float ysh[160][37];
  __shared__ float aoutsh[160];
  __shared__ float asc[36], bsc[36], bets[36], alps[36], w2s[36];
  __shared__ float psum[80], psq[80];

  for (int e = tid; e < 80 * 168; e += 512) {
    const int n = e / 168, k = e - 168 * n;
    l1t[n][k] = (k < 160) ? f2bf(l1_W[k * 80 + n]) : (unsigned short)0;
  }
  for (int e = tid; e < 160 * 36; e += 512) {
    ysh[e / 36][e % 36] = ws_y[(size_t)base * 180 + e];
  }
  if (tid < 36) {
    double s = 0.0, q = 0.0;
#pragma unroll
    for (int sh = 0; sh < NSHARD; sh++) {
      s += gstats[sh * SHARD_STRIDE + AU_SUM + tid];
      q += gstats[sh * SHARD_STRIDE + AU_SQ + tid];
    }
    const double m = s * (1.0 / ((double)NB * NK));
    const double var = q * (1.0 / ((double)NB * NK)) - m * m;
    const float rstd = (float)(1.0 / sqrt(var + 1e-8));
    const float g = au_gamma[tid] * rstd;
    asc[tid] = g; bsc[tid] = au_bbeta[tid] - (float)m * g;
    bets[tid] = au_beta[tid];
    alps[tid] = au_alpha[tid];
    w2s[tid] = au_W2[tid];
  }
  if (tid < 80) { psum[tid] = 0.f; psq[tid] = 0.f; }
  __syncthreads();

  const float bias2 = au_b2[0];
  if (tid < 160) {
    float acc = 0.f;
#pragma unroll
    for (int j = 0; j < 36; j++) {
      const float yv = ysh[tid][j];
      const float bn = yv * asc[j] + bsc[j];
      const float xn = sigm(bets[j] * bn);
      acc = fmaf(alps[j] * (1.f - xn) * yv + xn * yv, w2s[j], acc);
    }
    aoutsh[tid] = acc + bias2;
  }
  __syncthreads();

  for (int r = 0; r < 4; r++) {
    const int lm = r * 8 + wv;
    const int row = base + lm;
    const int iv = iid[row], cv = aid[row];
    const float ic = (lane < 32) ? item_tab[iv * NH + lane] : cate_tab[cv * NH + lane - 32];
    float fh0 = 0.f, fh1 = 0.f;
#pragma unroll
    for (int k = 0; k < NK; k++) {
      const int hik = ws_hi[row * NK + k];
      const int hak = ws_ha[row * NK + k];
      const int rvk = ws_hr[row * NK + k];
      const float wk = ws_w[row * NK + k];
      const float aok = aoutsh[lm * 5 + k];
      const float e = (lane < 32) ? item_tab[hik * NH + lane] : cate_tab[hak * NH + lane - 32];
      fh0 = fmaf(wk * e, aok, fh0);
      if (lane < 32) fh1 = fmaf(rate_tab[rvk * NH + lane], aok, fh1);
    }
    resb[lm][lane] = f2bf(ic);
    resb[lm][64 + lane] = f2bf(fh0);
    if (lane < 32) resb[lm][128 + lane] = f2bf(fh1);
  }
  __syncthreads();

  const int l15 = lane & 15, lhi = lane >> 4;
  for (int t = wv; t < 10; t += 8) {
    const int mt = t / 5, nt = t - 5 * mt;
    f32x4 acc = {0.f, 0.f, 0.f, 0.f};
#pragma unroll
    for (int ks = 0; ks < 5; ks++) {
      const int k0 = ks * 32 + lhi * 8;
      const bf16x8 a = *reinterpret_cast<const bf16x8*>(&resb[mt * 16 + l15][k0]);
      const bf16x8 b = *reinterpret_cast<const bf16x8*>(&l1t[nt * 16 + l15][k0]);
      acc = __builtin_amdgcn_mfma_f32_16x16x32_bf16(a, b, acc, 0, 0, 0);
    }
    const int n = nt * 16 + l15;
    const float bn = l1_b[n];
    float ls = 0.f, lq = 0.f;
#pragma unroll
    for (int reg = 0; reg < 4; reg++) {
      const int m = mt * 16 + 4 * lhi + reg;
      const float h = acc[reg] + bn;
      ws_h1[(size_t)(base + m) * 80 + n] = h;
      ls += h; lq += h * h;
    }
    atomicAdd(&psum[n], ls);
    atomicAdd(&psq[n], lq);
  }
  __syncthreads();
  if (tid < 80) {
    atomicAdd(&gstats[shard * SHARD_STRIDE + D1_SUM + tid], (double)psum[tid]);
    atomicAdd(&gstats[shard * SHARD_STRIDE + D1_SQ + tid], (double)psq[tid]);
  }
}

// ---- Kernel 5: dice2(h1), h @ l2_W via MFMA, d2 stats -----------------------
__global__ __launch_bounds__(512) void k5(
    const float* __restrict__ d1_alpha, const float* __restrict__ d1_beta,
    const float* __restrict__ d1_gamma, const float* __restrict__ d1_bbeta,
    const float* __restrict__ l2_W, const float* __restrict__ l2_b,
    const float* __restrict__ ws_h1,
    double* __restrict__ gstats,
    float* __restrict__ ws_h2)
{
  const int tid = threadIdx.x, lane = tid & 63, wv = tid >> 6;
  const int shard = blockIdx.x & (NSHARD - 1);
  __shared__ alignas(16) unsigned short l2t[48][104];
  __shared__ alignas(16) unsigned short h1b[32][104];
  __shared__ float a1[80], c1[80];
  __shared__ float psum[40], psq[40];

  for (int e = tid; e < 48 * 104; e += 512) {
    const int n = e / 104, k = e - 104 * n;
    l2t[n][k] = (n < 40 && k < 80) ? f2bf(l2_W[k * 40 + n]) : (unsigned short)0;
  }
  if (tid < 80) {
    double s = 0.0, q = 0.0;
#pragma unroll
    for (int sh = 0; sh < NSHARD; sh++) {
      s += gstats[sh * SHARD_STRIDE + D1_SUM + tid];
      q += gstats[sh * SHARD_STRIDE + D1_SQ + tid];
    }
    const double m = s * (1.0 / (double)NB);
    const double var = q * (1.0 / (double)NB) - m * m;
    const float rstd = (float)(1.0 / sqrt(var + 1e-8));
    const float g = d1_gamma[tid] * rstd;
    a1[tid] = g; c1[tid] = d1_bbeta[tid] - (float)m * g;
  }
  if (tid < 40) { psum[tid] = 0.f; psq[tid] = 0.f; }
  __syncthreads();

  for (int r = 0; r < 4; r++) {
    const int lm = r * 8 + wv;
    const int row = blockIdx.x * 32 + lm;
    {
      const float v = ws_h1[(size_t)row * 80 + lane];
      const float bn = v * a1[lane] + c1[lane];
      const float xn = sigm(d1_beta[lane] * bn);
      h1b[lm][lane] = f2bf(d1_alpha[lane] * (1.f - xn) * v + xn * v);
    }
    const int o = 64 + lane;
    if (lane < 16) {
      const float v = ws_h1[(size_t)row * 80 + o];
      const float bn = v * a1[o] + c1[o];
      const float xn = sigm(d1_beta[o] * bn);
      h1b[lm][o] = f2bf(d1_alpha[o] * (1.f - xn) * v + xn * v);
    } else if (lane < 32) {
      h1b[lm][o] = 0;
    }
  }
  __syncthreads();

  const int l15 = lane & 15, lhi = lane >> 4;
  for (int t = wv; t < 6; t += 8) {
    const int mt = t / 3, nt = t - 3 * mt;
    f32x4 acc = {0.f, 0.f, 0.f, 0.f};
#pragma unroll
    for (int ks = 0; ks < 3; ks++) {
      const int k0 = ks * 32 + lhi * 8;
      const bf16x8 a = *reinterpret_cast<const bf16x8*>(&h1b[mt * 16 + l15][k0]);
      const bf16x8 b = *reinterpret_cast<const bf16x8*>(&l2t[nt * 16 + l15][k0]);
      acc = __builtin_amdgcn_mfma_f32_16x16x32_bf16(a, b, acc, 0, 0, 0);
    }
    const int n = nt * 16 + l15;
    if (n < 40) {
      const float bn = l2_b[n];
      float ls = 0.f, lq = 0.f;
#pragma unroll
      for (int reg = 0; reg < 4; reg++) {
        const int m = mt * 16 + 4 * lhi + reg;
        const float h = acc[reg] + bn;
        ws_h2[(size_t)(blockIdx.x * 32 + m) * 40 + n] = h;
        ls += h; lq += h * h;
      }
      atomicAdd(&psum[n], ls);
      atomicAdd(&psq[n], lq);
    }
  }
  __syncthreads();
  if (tid < 40) {
    atomicAdd(&gstats[shard * SHARD_STRIDE + D2_SUM + tid], (double)psum[tid]);
    atomicAdd(&gstats[shard * SHARD_STRIDE + D2_SQ + tid], (double)psq[tid]);
  }
}

// ---- Kernel 7: dice2(h2), logits, probs, loss (+ last-block finalize) -------
__global__ __launch_bounds__(256) void k7(
    const int* __restrict__ lb,
    const float* __restrict__ d2_alpha, const float* __restrict__ d2_beta,
    const float* __restrict__ d2_gamma, const float* __restrict__ d2_bbeta,
    const float* __restrict__ l3_W, const float* __restrict__ l3_b,
    const float* __restrict__ ws_h2,
    double* __restrict__ gstats,
    float* __restrict__ out)
{
  const int tid = threadIdx.x, lane = tid & 63, wv = tid >> 6;
  __shared__ float a2[40], c2[40];
  __shared__ float wls[4];
  if (tid < 40) {
    double s = 0.0, q = 0.0;
#pragma unroll
    for (int sh = 0; sh < NSHARD; sh++) {
      s += gstats[sh * SHARD_STRIDE + D2_SUM + tid];
      q += gstats[sh * SHARD_STRIDE + D2_SQ + tid];
    }
    const double m = s * (1.0 / (double)NB);
    const double var = q * (1.0 / (double)NB) - m * m;
    const float rstd = (float)(1.0 / sqrt(var + 1e-8));
    const float g = d2_gamma[tid] * rstd;
    a2[tid] = g; c2[tid] = d2_bbeta[tid] - (float)m * g;
  }
  __syncthreads();

  float wj = 0, b2j = 0, c2j = 0, betaj = 0, alphaj = 0;
  if (lane < 40) {
    wj = l3_W[lane]; b2j = a2[lane]; c2j = c2[lane];
    betaj = d2_beta[lane]; alphaj = d2_alpha[lane];
  }
  const float b3 = l3_b[0];

  float lacc = 0.f;
  for (int r = 0; r < 4; r++) {
    const int row = blockIdx.x * 16 + r * 4 + wv;
    float p = 0.f;
    if (lane < 40) {
      const float v = ws_h2[(size_t)row * 40 + lane];
      const float bn = v * b2j + c2j;
      const float xn = sigm(betaj * bn);
      p = (alphaj * (1.f - xn) * v + xn * v) * wj;
    }
    const float logit = wsum64(p) + b3;
    if (lane == 0) {
      out[row] = 1.f / (1.f + expf(-logit));
      const float lab = (float)lb[row];
      lacc += fmaxf(logit, 0.f) - logit * lab + log1pf(expf(-fabsf(logit)));
    }
  }
  if (lane == 0) wls[wv] = lacc;
  __syncthreads();
  if (tid == 0) {
    double* g_loss = gstats + LOSS_OFF;
    unsigned int* g_cnt = (unsigned int*)(gstats + CNT_OFF);
    atomicAdd(g_loss, (double)(wls[0] + wls[1] + wls[2] + wls[3]));
    __threadfence();
    const unsigned prev = atomicAdd(g_cnt, 1u);
    if (prev == (unsigned)(gridDim.x - 1)) {
      const double tot = atomicAdd(g_loss, 0.0);
      out[NB] = (float)(tot * (1.0 / (double)NB));
    }
  }
}

} // namespace

extern "C" void kernel_launch(void* const* d_in, const int* in_sizes, int n_in,
                              void* d_out, int out_size, void* d_ws, size_t ws_size,
                              hipStream_t stream) {
  const int* iid       = (const int*)d_in[0];
  const int* aid       = (const int*)d_in[1];
  const int* lb        = (const int*)d_in[2];
  const int* hist_iid  = (const int*)d_in[3];
  const int* hist_aid  = (const int*)d_in[4];
  const int* hist_rate = (const int*)d_in[5];
  const float* item_tab = (const float*)d_in[6];
  const float* cate_tab = (const float*)d_in[7];
  const float* rate_tab = (const float*)d_in[8];
  const float* au_W1    = (const float*)d_in[9];
  const float* au_b1    = (const float*)d_in[10];
  const float* au_alpha = (const float*)d_in[11];
  const float* au_beta  = (const float*)d_in[12];
  const float* au_gamma = (const float*)d_in[13];
  const float* au_bbeta = (const float*)d_in[14];
  const float* au_W2    = (const float*)d_in[15];
  const float* au_b2    = (const float*)d_in[16];
  const float* l1_W     = (const float*)d_in[17];
  const float* l1_b     = (const float*)d_in[18];
  const float* d1_alpha = (const float*)d_in[19];
  const float* d1_beta  = (const float*)d_in[20];
  const float* d1_gamma = (const float*)d_in[21];
  const float* d1_bbeta = (const float*)d_in[22];
  const float* l2_W     = (const float*)d_in[23];
  const float* l2_b     = (const float*)d_in[24];
  const float* d2_alpha = (const float*)d_in[25];
  const float* d2_beta  = (const float*)d_in[26];
  const float* d2_gamma = (const float*)d_in[27];
  const float* d2_bbeta = (const float*)d_in[28];
  const float* l3_W     = (const float*)d_in[29];
  const float* l3_b     = (const float*)d_in[30];
  float* out = (float*)d_out;

  double* gstats = (double*)d_ws;
  float* fbase  = (float*)((char*)d_ws + 32768);
  float* ws_y   = fbase;                       // NB*180
  float* ws_w   = fbase + (size_t)NB * 180;    // NB*5
  float* ws_h1  = fbase + (size_t)NB * 185;    // NB*80
  float* ws_h2  = fbase + (size_t)NB * 265;    // NB*40
  int*   ws_hi  = (int*)(fbase + (size_t)NB * 305);  // NB*5
  int*   ws_ha  = ws_hi + (size_t)NB * NK;
  int*   ws_hr  = ws_ha + (size_t)NB * NK;

  hipMemsetAsync(d_ws, 0, (CNT_OFF + 2) * sizeof(double), stream);
  k1<<<dim3(NB / 16), 512, 0, stream>>>(iid, aid, hist_iid, hist_aid, hist_rate,
                              item_tab, cate_tab, au_W1, au_b1,
                              ws_y, ws_w, ws_hi, ws_ha, ws_hr, gstats);
  k3<<<dim3(NB / 32), 512, 0, stream>>>(iid, aid, item_tab, cate_tab, rate_tab,
                              au_alpha, au_beta, au_gamma, au_bbeta, au_W2, au_b2,
                              l1_W, l1_b, ws_y, ws_w, ws_hi, ws_ha, ws_hr,
                              gstats, ws_h1);
  k5<<<dim3(NB / 32), 512, 0, stream>>>(d1_alpha, d1_beta, d1_gamma, d1_bbeta, l2_W, l2_b,
                              ws_h1, gstats, ws_h2);
  k7<<<dim3(NB / 16), 256, 0, stream>>>(lb, d2_alpha, d2_beta, d2_gamma, d2_bbeta, l3_W, l3_b,
                              ws_h2, gstats, out);
}

// Round 11
// 151.521 us; speedup vs baseline: 2.0226x; 1.0424x over previous
//
#include <hip/hip_runtime.h>
#include <cmath>

namespace {
constexpr int NB = 16384;
constexpr int NS = 50;
constexpr int NK = 5;
constexpr int NH = 32;

// sharded f64 stat layout (8 shards x 312 doubles) + loss + counter
constexpr int AU_SUM = 0, AU_SQ = 36, D1_SUM = 72, D1_SQ = 152, D2_SUM = 232, D2_SQ = 272;
constexpr int SHARD_STRIDE = 312;
constexpr int NSHARD = 8;
constexpr int LOSS_OFF = SHARD_STRIDE * NSHARD;      // 2496
constexpr int CNT_OFF  = LOSS_OFF + 1;               // 2497 (as int storage)

typedef __attribute__((ext_vector_type(8))) short bf16x8;
typedef __attribute__((ext_vector_type(4))) float f32x4;

__device__ __forceinline__ float wsum64(float v) {
#pragma unroll
  for (int off = 32; off; off >>= 1) v += __shfl_xor(v, off, 64);
  return v;
}

__device__ __forceinline__ float sigm(float x) { return 1.0f / (1.0f + expf(-x)); }

__device__ __forceinline__ unsigned short f2bf(float f) {
  union { float f; unsigned u; } v; v.f = f;
  unsigned r = v.u + 0x7fffu + ((v.u >> 16) & 1u);
  return (unsigned short)(r >> 16);
}

__device__ __forceinline__ float bf2f(unsigned short b) {
  union { unsigned u; float f; } v; v.u = ((unsigned)b) << 16;
  return v.f;
}

// ---- Kernel 1: embeddings, sim, top-5, x @ au_W1 via MFMA, au-BN stats ------
// R10 structure (passed). Additionally persists bf16 wk*e rows (ws_xw) and
// bf16 ic rows (ws_ic) so k3 needs no scattered table gathers.
__global__ __launch_bounds__(512) void k1(
    const int* __restrict__ iid, const int* __restrict__ aid,
    const int* __restrict__ hist_iid, const int* __restrict__ hist_aid,
    const int* __restrict__ hist_rate,
    const float* __restrict__ item_tab, const float* __restrict__ cate_tab,
    const float* __restrict__ au_W1, const float* __restrict__ au_b1,
    float* __restrict__ ws_y,
    unsigned short* __restrict__ ws_xw, unsigned short* __restrict__ ws_ic,
    int* __restrict__ ws_hr,
    double* __restrict__ gstats)
{
  const int tid = threadIdx.x;
  const int lane = tid & 63;
  const int wv = tid >> 6;
  const int shard = blockIdx.x & (NSHARD - 1);

  __shared__ alignas(16) unsigned short w1t[48][136];
  __shared__ alignas(16) unsigned short xb[80][136];
  __shared__ float icsh[8][64];
  __shared__ float crossm[80];
  __shared__ float w1c[36], b1s[36];
  __shared__ float psum[36], psq[36];

  for (int e = tid; e < 48 * 136; e += 512) {
    const int n = e / 136, k = e - 136 * n;
    float v = 0.f;
    if (n < 36 && k < 128) {
      const int i = (k < 64) ? k : (k + 1);
      v = au_W1[i * 36 + n];
    }
    w1t[n][k] = f2bf(v);
  }
  if (tid < 36) {
    w1c[tid] = au_W1[64 * 36 + tid];
    b1s[tid] = au_b1[tid];
    psum[tid] = 0.f; psq[tid] = 0.f;
  }

  for (int r = 0; r < 2; r++) {
    const int lm = r * 8 + wv;
    const int row = blockIdx.x * 16 + lm;

    const int iv = iid[row];
    const int cv = aid[row];
    const float ic = (lane < 32) ? item_tab[iv * NH + lane] : cate_tab[cv * NH + lane - 32];
    icsh[wv][lane] = ic;
    const float n1 = sqrtf(wsum64(ic * ic));

    int hi = 0, ha = 0, rv = 0;
    float dotv = 0.f, sim = -INFINITY;
    if (lane < NS) {
      hi = hist_iid[row * NS + lane];
      ha = hist_aid[row * NS + lane];
      rv = hist_rate[row * NS + lane];
      const float4* ip = reinterpret_cast<const float4*>(item_tab + (size_t)hi * NH);
      const float4* cp = reinterpret_cast<const float4*>(cate_tab + (size_t)ha * NH);
      const float* ics = icsh[wv];
      float n2sq = 0.f;
#pragma unroll
      for (int q = 0; q < 8; q++) {
        float4 a = ip[q];
        dotv += ics[4*q+0]*a.x + ics[4*q+1]*a.y + ics[4*q+2]*a.z + ics[4*q+3]*a.w;
        n2sq += a.x*a.x + a.y*a.y + a.z*a.z + a.w*a.w;
      }
#pragma unroll
      for (int q = 0; q < 8; q++) {
        float4 a = cp[q];
        dotv += ics[32+4*q+0]*a.x + ics[32+4*q+1]*a.y + ics[32+4*q+2]*a.z + ics[32+4*q+3]*a.w;
        n2sq += a.x*a.x + a.y*a.y + a.z*a.z + a.w*a.w;
      }
      sim = dotv / fmaxf(n1 * sqrtf(n2sq), 1e-8f);
    }

    // rank-based top-5: desc value, asc index (== jax.lax.top_k)
    int rank = 0;
#pragma unroll
    for (int j = 0; j < NS; j++) {
      const float sj = __shfl(sim, j, 64);
      rank += (sj > sim) || (sj == sim && j < lane);
    }
    int tk[NK]; float vals[NK];
#pragma unroll
    for (int k = 0; k < NK; k++) {
      const unsigned long long mk = __ballot((lane < NS) && (rank == k));
      tk[k] = __ffsll((long long)mk) - 1;
    }
#pragma unroll
    for (int k = 0; k < NK; k++) vals[k] = __shfl(sim, tk[k], 64);

    const float ssumw = vals[0] + vals[1] + vals[2] + vals[3] + vals[4] + 1e-8f;
    const unsigned short icb = f2bf(ic);
    ws_ic[(size_t)row * 64 + lane] = icb;
#pragma unroll
    for (int k = 0; k < NK; k++) {
      const float wk = vals[k] / ssumw;
      const float crossk = wk * __shfl(dotv, tk[k], 64);
      const int hik = __shfl(hi, tk[k], 64);
      const int hak = __shfl(ha, tk[k], 64);
      const int rvk = __shfl(rv, tk[k], 64);
      const float e = (lane < 32) ? item_tab[hik * NH + lane] : cate_tab[hak * NH + lane - 32];
      const int m = lm * 5 + k;
      const unsigned short xwb = f2bf(wk * e);
      xb[m][lane] = xwb;
      xb[m][64 + lane] = icb;
      ws_xw[((size_t)row * NK + k) * 64 + lane] = xwb;
      if (lane == 0) crossm[m] = crossk;
      if (lane == k) ws_hr[row * NK + k] = rvk;
    }
  }
  __syncthreads();

  // MFMA GEMM: M=80 (5 tiles), N=36->48 (3 tiles), K=128 (4 steps)
  const int l15 = lane & 15, lhi = lane >> 4;
  for (int t = wv; t < 15; t += 8) {
    const int mt = t / 3, nt = t - 3 * mt;
    f32x4 acc = {0.f, 0.f, 0.f, 0.f};
#pragma unroll
    for (int ks = 0; ks < 4; ks++) {
      const int k0 = ks * 32 + lhi * 8;
      const bf16x8 a = *reinterpret_cast<const bf16x8*>(&xb[mt * 16 + l15][k0]);
      const bf16x8 b = *reinterpret_cast<const bf16x8*>(&w1t[nt * 16 + l15][k0]);
      acc = __builtin_amdgcn_mfma_f32_16x16x32_bf16(a, b, acc, 0, 0, 0);
    }
    const int n = nt * 16 + l15;
    if (n < 36) {
      const float w1cn = w1c[n], b1n = b1s[n];
      float ls = 0.f, lq = 0.f;
#pragma unroll
      for (int reg = 0; reg < 4; reg++) {
        const int m = mt * 16 + 4 * lhi + reg;
        const float y = acc[reg] + b1n + crossm[m] * w1cn;
        ws_y[(size_t)(blockIdx.x * 80 + m) * 36 + n] = y;
        ls += y; lq += y * y;
      }
      atomicAdd(&psum[n], ls);
      atomicAdd(&psq[n], lq);
    }
  }
  __syncthreads();
  if (tid < 36) {
    atomicAdd(&gstats[shard * SHARD_STRIDE + AU_SUM + tid], (double)psum[tid]);
    atomicAdd(&gstats[shard * SHARD_STRIDE + AU_SQ + tid], (double)psq[tid]);
  }
}

// ---- Kernel 3: dice3 (LDS-staged aout), final_hist, res @ l1_W, d1 stats ----
// No scattered table gathers: reads persisted ws_xw/ws_ic (coalesced bf16)
// + L1-hot rate_tab (10 rows).
__global__ __launch_bounds__(512) void k3(
    const float* __restrict__ rate_tab,
    const float* __restrict__ au_alpha, const float* __restrict__ au_beta,
    const float* __restrict__ au_gamma, const float* __restrict__ au_bbeta,
    const float* __restrict__ au_W2, const float* __restrict__ au_b2,
    const float* __restrict__ l1_W, const float* __restrict__ l1_b,
    const float* __restrict__ ws_y,
    const unsigned short* __restrict__ ws_xw, const unsigned short* __restrict__ ws_ic,
    const int* __restrict__ ws_hr,
    double* __restrict__ gstats,
    float* __restrict__ ws_h1)
{
  const int tid = threadIdx.x, lane = tid & 63, wv = tid >> 6;
  const int base = blockIdx.x * 32;
  const int shard = blockIdx.x & (NSHARD - 1);
  __shared__ alignas(16) unsigned short l1t[80][168];
  __shared__ alignas(16) unsigned short resb[32][168];
  __shared__ float ysh[160][37];
  __shared__ float aoutsh[160];
  __shared__ float asc[36], bsc[36], bets[36], alps[36], w2s[36];
  __shared__ float psum[80], psq[80];

  for (int e = tid; e < 80 * 168; e += 512) {
    const int n = e / 168, k = e - 168 * n;
    l1t[n][k] = (k < 160) ? f2bf(l1_W[k * 80 + n]) : (unsigned short)0;
  }
  for (int e = tid; e < 160 * 36; e += 512) {
    ysh[e / 36][e % 36] = ws_y[(size_t)base * 180 + e];
  }
  if (tid < 36) {
    double s = 0.0, q = 0.0;
#pragma unroll
    for (int sh = 0; sh < NSHARD; sh++) {
      s += gstats[sh * SHARD_STRIDE + AU_SUM + tid];
      q += gstats[sh * SHARD_STRIDE + AU_SQ + tid];
    }
    const double m = s * (1.0 / ((double)NB * NK));
    const double var = q * (1.0 / ((double)NB * NK)) - m * m;
    const float rstd = (float)(1.0 / sqrt(var + 1e-8));
    const float g = au_gamma[tid] * rstd;
    asc[tid] = g; bsc[tid] = au_bbeta[tid] - (float)m * g;
    bets[tid] = au_beta[tid];
    alps[tid] = au_alpha[tid];
    w2s[tid] = au_W2[tid];
  }
  if (tid < 80) { psum[tid] = 0.f; psq[tid] = 0.f; }
  __syncthreads();

  const float bias2 = au_b2[0];
  if (tid < 160) {
    float acc = 0.f;
#pragma unroll
    for (int j = 0; j < 36; j++) {
      const float yv = ysh[tid][j];
      const float bn = yv * asc[j] + bsc[j];
      const float xn = sigm(bets[j] * bn);
      acc = fmaf(alps[j] * (1.f - xn) * yv + xn * yv, w2s[j], acc);
    }
    aoutsh[tid] = acc + bias2;
  }
  __syncthreads();

  for (int r = 0; r < 4; r++) {
    const int lm = r * 8 + wv;
    const int row = base + lm;
    const unsigned short icb = ws_ic[(size_t)row * 64 + lane];
    float fh0 = 0.f, fh1 = 0.f;
#pragma unroll
    for (int k = 0; k < NK; k++) {
      const float aok = aoutsh[lm * 5 + k];
      const unsigned short xwb = ws_xw[((size_t)row * NK + k) * 64 + lane];
      fh0 = fmaf(bf2f(xwb), aok, fh0);
      if (lane < 32) {
        const int rvk = ws_hr[row * NK + k];
        fh1 = fmaf(rate_tab[rvk * NH + lane], aok, fh1);
      }
    }
    resb[lm][lane] = icb;
    resb[lm][64 + lane] = f2bf(fh0);
    if (lane < 32) resb[lm][128 + lane] = f2bf(fh1);
  }
  __syncthreads();

  const int l15 = lane & 15, lhi = lane >> 4;
  for (int t = wv; t < 10; t += 8) {
    const int mt = t / 5, nt = t - 5 * mt;
    f32x4 acc = {0.f, 0.f, 0.f, 0.f};
#pragma unroll
    for (int ks = 0; ks < 5; ks++) {
      const int k0 = ks * 32 + lhi * 8;
      const bf16x8 a = *reinterpret_cast<const bf16x8*>(&resb[mt * 16 + l15][k0]);
      const bf16x8 b = *reinterpret_cast<const bf16x8*>(&l1t[nt * 16 + l15][k0]);
      acc = __builtin_amdgcn_mfma_f32_16x16x32_bf16(a, b, acc, 0, 0, 0);
    }
    const int n = nt * 16 + l15;
    const float bn = l1_b[n];
    float ls = 0.f, lq = 0.f;
#pragma unroll
    for (int reg = 0; reg < 4; reg++) {
      const int m = mt * 16 + 4 * lhi + reg;
      const float h = acc[reg] + bn;
      ws_h1[(size_t)(base + m) * 80 + n] = h;
      ls += h; lq += h * h;
    }
    atomicAdd(&psum[n], ls);
    atomicAdd(&psq[n], lq);
  }
  __syncthreads();
  if (tid < 80) {
    atomicAdd(&gstats[shard * SHARD_STRIDE + D1_SUM + tid], (double)psum[tid]);
    atomicAdd(&gstats[shard * SHARD_STRIDE + D1_SQ + tid], (double)psq[tid]);
  }
}

// ---- Kernel 5: dice2(h1), h @ l2_W via MFMA, d2 stats -----------------------
__global__ __launch_bounds__(512) void k5(
    const float* __restrict__ d1_alpha, const float* __restrict__ d1_beta,
    const float* __restrict__ d1_gamma, const float* __restrict__ d1_bbeta,
    const float* __restrict__ l2_W, const float* __restrict__ l2_b,
    const float* __restrict__ ws_h1,
    double* __restrict__ gstats,
    float* __restrict__ ws_h2)
{
  const int tid = threadIdx.x, lane = tid & 63, wv = tid >> 6;
  const int shard = blockIdx.x & (NSHARD - 1);
  __shared__ alignas(16) unsigned short l2t[48][104];
  __shared__ alignas(16) unsigned short h1b[32][104];
  __shared__ float a1[80], c1[80];
  __shared__ float psum[40], psq[40];

  for (int e = tid; e < 48 * 104; e += 512) {
    const int n = e / 104, k = e - 104 * n;
    l2t[n][k] = (n < 40 && k < 80) ? f2bf(l2_W[k * 40 + n]) : (unsigned short)0;
  }
  if (tid < 80) {
    double s = 0.0, q = 0.0;
#pragma unroll
    for (int sh = 0; sh < NSHARD; sh++) {
      s += gstats[sh * SHARD_STRIDE + D1_SUM + tid];
      q += gstats[sh * SHARD_STRIDE + D1_SQ + tid];
    }
    const double m = s * (1.0 / (double)NB);
    const double var = q * (1.0 / (double)NB) - m * m;
    const float rstd = (float)(1.0 / sqrt(var + 1e-8));
    const float g = d1_gamma[tid] * rstd;
    a1[tid] = g; c1[tid] = d1_bbeta[tid] - (float)m * g;
  }
  if (tid < 40) { psum[tid] = 0.f; psq[tid] = 0.f; }
  __syncthreads();

  for (int r = 0; r < 4; r++) {
    const int lm = r * 8 + wv;
    const int row = blockIdx.x * 32 + lm;
    {
      const float v = ws_h1[(size_t)row * 80 + lane];
      const float bn = v * a1[lane] + c1[lane];
      const float xn = sigm(d1_beta[lane] * bn);
      h1b[lm][lane] = f2bf(d1_alpha[lane] * (1.f - xn) * v + xn * v);
    }
    const int o = 64 + lane;
    if (lane < 16) {
      const float v = ws_h1[(size_t)row * 80 + o];
      const float bn = v * a1[o] + c1[o];
      const float xn = sigm(d1_beta[o] * bn);
      h1b[lm][o] = f2bf(d1_alpha[o] * (1.f - xn) * v + xn * v);
    } else if (lane < 32) {
      h1b[lm][o] = 0;
    }
  }
  __syncthreads();

  const int l15 = lane & 15, lhi = lane >> 4;
  for (int t = wv; t < 6; t += 8) {
    const int mt = t / 3, nt = t - 3 * mt;
    f32x4 acc = {0.f, 0.f, 0.f, 0.f};
#pragma unroll
    for (int ks = 0; ks < 3; ks++) {
      const int k0 = ks * 32 + lhi * 8;
      const bf16x8 a = *reinterpret_cast<const bf16x8*>(&h1b[mt * 16 + l15][k0]);
      const bf16x8 b = *reinterpret_cast<const bf16x8*>(&l2t[nt * 16 + l15][k0]);
      acc = __builtin_amdgcn_mfma_f32_16x16x32_bf16(a, b, acc, 0, 0, 0);
    }
    const int n = nt * 16 + l15;
    if (n < 40) {
      const float bn = l2_b[n];
      float ls = 0.f, lq = 0.f;
#pragma unroll
      for (int reg = 0; reg < 4; reg++) {
        const int m = mt * 16 + 4 * lhi + reg;
        const float h = acc[reg] + bn;
        ws_h2[(size_t)(blockIdx.x * 32 + m) * 40 + n] = h;
        ls += h; lq += h * h;
      }
      atomicAdd(&psum[n], ls);
      atomicAdd(&psq[n], lq);
    }
  }
  __syncthreads();
  if (tid < 40) {
    atomicAdd(&gstats[shard * SHARD_STRIDE + D2_SUM + tid], (double)psum[tid]);
    atomicAdd(&gstats[shard * SHARD_STRIDE + D2_SQ + tid], (double)psq[tid]);
  }
}

// ---- Kernel 7: dice2(h2), logits, probs, loss (+ last-block finalize) -------
__global__ __launch_bounds__(256) void k7(
    const int* __restrict__ lb,
    const float* __restrict__ d2_alpha, const float* __restrict__ d2_beta,
    const float* __restrict__ d2_gamma, const float* __restrict__ d2_bbeta,
    const float* __restrict__ l3_W, const float* __restrict__ l3_b,
    const float* __restrict__ ws_h2,
    double* __restrict__ gstats,
    float* __restrict__ out)
{
  const int tid = threadIdx.x, lane = tid & 63, wv = tid >> 6;
  __shared__ float a2[40], c2[40];
  __shared__ float wls[4];
  if (tid < 40) {
    double s = 0.0, q = 0.0;
#pragma unroll
    for (int sh = 0; sh < NSHARD; sh++) {
      s += gstats[sh * SHARD_STRIDE + D2_SUM + tid];
      q += gstats[sh * SHARD_STRIDE + D2_SQ + tid];
    }
    const double m = s * (1.0 / (double)NB);
    const double var = q * (1.0 / (double)NB) - m * m;
    const float rstd = (float)(1.0 / sqrt(var + 1e-8));
    const float g = d2_gamma[tid] * rstd;
    a2[tid] = g; c2[tid] = d2_bbeta[tid] - (float)m * g;
  }
  __syncthreads();

  float wj = 0, b2j = 0, c2j = 0, betaj = 0, alphaj = 0;
  if (lane < 40) {
    wj = l3_W[lane]; b2j = a2[lane]; c2j = c2[lane];
    betaj = d2_beta[lane]; alphaj = d2_alpha[lane];
  }
  const float b3 = l3_b[0];

  float lacc = 0.f;
  for (int r = 0; r < 4; r++) {
    const int row = blockIdx.x * 16 + r * 4 + wv;
    float p = 0.f;
    if (lane < 40) {
      const float v = ws_h2[(size_t)row * 40 + lane];
      const float bn = v * b2j + c2j;
      const float xn = sigm(betaj * bn);
      p = (alphaj * (1.f - xn) * v + xn * v) * wj;
    }
    const float logit = wsum64(p) + b3;
    if (lane == 0) {
      out[row] = 1.f / (1.f + expf(-logit));
      const float lab = (float)lb[row];
      lacc += fmaxf(logit, 0.f) - logit * lab + log1pf(expf(-fabsf(logit)));
    }
  }
  if (lane == 0) wls[wv] = lacc;
  __syncthreads();
  if (tid == 0) {
    double* g_loss = gstats + LOSS_OFF;
    unsigned int* g_cnt = (unsigned int*)(gstats + CNT_OFF);
    atomicAdd(g_loss, (double)(wls[0] + wls[1] + wls[2] + wls[3]));
    __threadfence();
    const unsigned prev = atomicAdd(g_cnt, 1u);
    if (prev == (unsigned)(gridDim.x - 1)) {
      const double tot = atomicAdd(g_loss, 0.0);
      out[NB] = (float)(tot * (1.0 / (double)NB));
    }
  }
}

} // namespace

extern "C" void kernel_launch(void* const* d_in, const int* in_sizes, int n_in,
                              void* d_out, int out_size, void* d_ws, size_t ws_size,
                              hipStream_t stream) {
  const int* iid       = (const int*)d_in[0];
  const int* aid       = (const int*)d_in[1];
  const int* lb        = (const int*)d_in[2];
  const int* hist_iid  = (const int*)d_in[3];
  const int* hist_aid  = (const int*)d_in[4];
  const int* hist_rate = (const int*)d_in[5];
  const float* item_tab = (const float*)d_in[6];
  const float* cate_tab = (const float*)d_in[7];
  const float* rate_tab = (const float*)d_in[8];
  const float* au_W1    = (const float*)d_in[9];
  const float* au_b1    = (const float*)d_in[10];
  const float* au_alpha = (const float*)d_in[11];
  const float* au_beta  = (const float*)d_in[12];
  const float* au_gamma = (const float*)d_in[13];
  const float* au_bbeta = (const float*)d_in[14];
  const float* au_W2    = (const float*)d_in[15];
  const float* au_b2    = (const float*)d_in[16];
  const float* l1_W     = (const float*)d_in[17];
  const float* l1_b     = (const float*)d_in[18];
  const float* d1_alpha = (const float*)d_in[19];
  const float* d1_beta  = (const float*)d_in[20];
  const float* d1_gamma = (const float*)d_in[21];
  const float* d1_bbeta = (const float*)d_in[22];
  const float* l2_W     = (const float*)d_in[23];
  const float* l2_b     = (const float*)d_in[24];
  const float* d2_alpha = (const float*)d_in[25];
  const float* d2_beta  = (const float*)d_in[26];
  const float* d2_gamma = (const float*)d_in[27];
  const float* d2_bbeta = (const float*)d_in[28];
  const float* l3_W     = (const float*)d_in[29];
  const float* l3_b     = (const float*)d_in[30];
  float* out = (float*)d_out;

  double* gstats = (double*)d_ws;
  float* fbase  = (float*)((char*)d_ws + 32768);
  float* ws_y   = fbase;                                  // NB*180 f32
  float* ws_h1  = fbase + (size_t)NB * 180;               // NB*80 f32
  float* ws_h2  = ws_h1 + (size_t)NB * 80;                // NB*40 f32
  int*   ws_hr  = (int*)(ws_h2 + (size_t)NB * 40);        // NB*5 int
  unsigned short* ws_xw = (unsigned short*)(ws_hr + (size_t)NB * NK); // NB*5*64 bf16
  unsigned short* ws_ic = ws_xw + (size_t)NB * NK * 64;   // NB*64 bf16

  hipMemsetAsync(d_ws, 0, (CNT_OFF + 2) * sizeof(double), stream);
  k1<<<dim3(NB / 16), 512, 0, stream>>>(iid, aid, hist_iid, hist_aid, hist_rate,
                              item_tab, cate_tab, au_W1, au_b1,
                              ws_y, ws_xw, ws_ic, ws_hr, gstats);
  k3<<<dim3(NB / 32), 512, 0, stream>>>(rate_tab,
                              au_alpha, au_beta, au_gamma, au_bbeta, au_W2, au_b2,
                              l1_W, l1_b, ws_y, ws_xw, ws_ic, ws_hr,
                              gstats, ws_h1);
  k5<<<dim3(NB / 32), 512, 0, stream>>>(d1_alpha, d1_beta, d1_gamma, d1_bbeta, l2_W, l2_b,
                              ws_h1, gstats, ws_h2);
  k7<<<dim3(NB / 16), 256, 0, stream>>>(lb, d2_alpha, d2_beta, d2_gamma, d2_bbeta, l3_W, l3_b,
                              ws_h2, gstats, out);
}